// Round 2
// baseline (1180.413 us; speedup 1.0000x reference)
//
#include <hip/hip_runtime.h>
#include <stdint.h>

#define NNODES 100000
#define NEDGES 1600000

typedef unsigned short ushort_t;

__device__ __forceinline__ float b2f(ushort_t u) {
  union { float f; uint32_t i; } v; v.i = ((uint32_t)u) << 16; return v.f;
}
__device__ __forceinline__ ushort_t f2b(float f) {
  union { float f; uint32_t i; } v; v.f = f;
  uint32_t r = (v.i + 0x7fffu + ((v.i >> 16) & 1u)) >> 16;
  return (ushort_t)r;
}
__device__ __forceinline__ int clampn(int i) {
  return i < 0 ? 0 : (i >= NNODES ? NNODES - 1 : i);
}

// ---- dtype detection (deterministic, once per call) ----
// flags[0] = 1 if float data is bf16, 0 if f32
// flags[1] = 1 if edge_index is int64, 0 if int32
__global__ void detect_k(const uint32_t* __restrict__ x, const uint32_t* __restrict__ ei,
                         int* __restrict__ flags) {
  if (blockIdx.x == 0 && threadIdx.x == 0) {
    int cf = 0, ci = 0;
    for (int i = 0; i < 256; ++i) {
      uint32_t u = x[i];
      uint32_t e = (u >> 7) & 0xFFu;        // exponent field of LOW half viewed as bf16
      if (e >= 100u && e <= 141u) cf++;      // plausible bf16 exponent for ~N(0,1) data
      if (ei[2 * i + 1] == 0u) ci++;         // int64 high words are 0
    }
    flags[0] = (cf >= 128) ? 1 : 0;
    flags[1] = (ci >= 128) ? 1 : 0;
  }
}

__global__ void zero_i32(int* __restrict__ p, int n) {
  int i = blockIdx.x * blockDim.x + threadIdx.x;
  if (i < n) p[i] = 0;
}

__global__ void hist_k(const uint32_t* __restrict__ ei, int* __restrict__ deg,
                       const int* __restrict__ flags) {
  int e = blockIdx.x * blockDim.x + threadIdx.x;
  if (e >= NEDGES) return;
  int i64 = flags[1];
  int d = i64 ? (int)ei[2 * (size_t)NEDGES + 2 * (size_t)e] : (int)ei[(size_t)NEDGES + e];
  atomicAdd(&deg[clampn(d)], 1);
}

__global__ __launch_bounds__(1024) void scan_k(const int* __restrict__ deg, int* __restrict__ offs,
                                               int* __restrict__ cursor, float* __restrict__ invdeg, int n) {
  __shared__ int wsum[16];
  __shared__ int carry_sh;
  int tid = threadIdx.x;
  int lane = tid & 63, wid = tid >> 6;
  if (tid == 0) carry_sh = 0;
  __syncthreads();
  for (int base = 0; base < n; base += 1024) {
    int i = base + tid;
    int v = (i < n) ? deg[i] : 0;
    int s = v;
    #pragma unroll
    for (int d = 1; d < 64; d <<= 1) {
      int t = __shfl_up(s, d);
      if (lane >= d) s += t;
    }
    __syncthreads();               // protect wsum from previous iteration reads
    if (lane == 63) wsum[wid] = s;
    __syncthreads();
    int wprefix = 0, total = 0;
    #pragma unroll
    for (int w = 0; w < 16; ++w) {
      int ws_ = wsum[w];
      if (w < wid) wprefix += ws_;
      total += ws_;
    }
    int carry = carry_sh;
    if (i < n) {
      int excl = carry + wprefix + s - v;
      offs[i] = excl;
      cursor[i] = excl;
      invdeg[i] = 1.0f / fmaxf((float)v, 1.0f);
    }
    __syncthreads();
    if (tid == 0) carry_sh = carry + total;
  }
  __syncthreads();
  if (tid == 0) offs[n] = carry_sh;
}

__global__ void scatter_k(const uint32_t* __restrict__ ei, int* __restrict__ cursor,
                          int* __restrict__ csr, const int* __restrict__ flags) {
  int e = blockIdx.x * blockDim.x + threadIdx.x;
  if (e >= NEDGES) return;
  int i64 = flags[1];
  int s, d;
  if (i64) {
    s = (int)ei[2 * (size_t)e];
    d = (int)ei[2 * (size_t)NEDGES + 2 * (size_t)e];
  } else {
    s = (int)ei[e];
    d = (int)ei[(size_t)NEDGES + e];
  }
  int p = atomicAdd(&cursor[clampn(d)], 1);
  if (p >= 0 && p < NEDGES) csr[p] = clampn(s);
}

// ---- dtype-gated conversion kernels ----
template <bool BF16>
__global__ void cvt_in_k(const void* __restrict__ src, float* __restrict__ dst, int n,
                         const int* __restrict__ flags) {
  if (flags[0] != (BF16 ? 1 : 0)) return;
  int i = blockIdx.x * blockDim.x + threadIdx.x;
  if (i < n) dst[i] = BF16 ? b2f(((const ushort_t*)src)[i]) : ((const float*)src)[i];
}

template <bool BF16>
__global__ void cvt_out_k(const float* __restrict__ src, void* __restrict__ dst, int n,
                          const int* __restrict__ flags) {
  if (flags[0] != (BF16 ? 1 : 0)) return;
  int i = blockIdx.x * blockDim.x + threadIdx.x;
  if (i < n) {
    if constexpr (BF16) ((ushort_t*)dst)[i] = f2b(src[i]);
    else ((float*)dst)[i] = src[i];
  }
}

struct WPtrs { const void* p[18]; int sz[18]; int off[18]; };

template <bool BF16>
__global__ void cvt_w_k(WPtrs w, float* __restrict__ dst, const int* __restrict__ flags) {
  if (flags[0] != (BF16 ? 1 : 0)) return;
  int a = blockIdx.x;
  int sz = w.sz[a], off = w.off[a];
  for (int t = threadIdx.x; t < sz; t += blockDim.x) {
    dst[off + t] = BF16 ? b2f(((const ushort_t*)w.p[a])[t]) : ((const float*)w.p[a])[t];
  }
}

// ---- f32 pipeline: one wave per destination node; lane = feature ----
template <int F, bool ADD_U>
__global__ __launch_bounds__(256) void agg_k(const float* __restrict__ feat, const int* __restrict__ csr,
                                             const int* __restrict__ offs, const float* __restrict__ invdeg,
                                             const float* __restrict__ u, float* __restrict__ out) {
  int lane = threadIdx.x & 63;
  int n = (blockIdx.x * blockDim.x + threadIdx.x) >> 6;
  if (n >= NNODES) return;
  int k0 = offs[n], k1 = offs[n + 1];
  float acc = 0.f;
  int k = k0;
  for (; k + 4 <= k1; k += 4) {
    int n0 = csr[k], n1 = csr[k + 1], n2 = csr[k + 2], n3 = csr[k + 3];
    if (lane < F) {
      acc += feat[(size_t)n0 * F + lane];
      acc += feat[(size_t)n1 * F + lane];
      acc += feat[(size_t)n2 * F + lane];
      acc += feat[(size_t)n3 * F + lane];
    }
  }
  for (; k < k1; ++k) {
    int nn = csr[k];
    if (lane < F) acc += feat[(size_t)nn * F + lane];
  }
  if (lane < F) {
    float val = acc * invdeg[n];
    if constexpr (ADD_U) val += u[(size_t)n * F + lane];
    out[(size_t)n * F + lane] = val;
  }
}

// One wave per node; lane = output column; weight columns in VGPRs.
// DUAL=false: C1 = act(A@W1 + B@W2 + bias)
// DUAL=true : C1 = A@W1 ; C2 = A@W2 + bias
template <int F_IN, int F_OUT, bool DUAL, bool RELU>
__global__ __launch_bounds__(256) void gemm_k(const float* __restrict__ A, const float* __restrict__ B,
                                              const float* __restrict__ W1, const float* __restrict__ W2,
                                              const float* __restrict__ bias,
                                              float* __restrict__ C1, float* __restrict__ C2) {
  int lane = threadIdx.x & 63;
  int wav = (blockIdx.x * blockDim.x + threadIdx.x) >> 6;
  int nw = (gridDim.x * blockDim.x) >> 6;
  int j = (lane < F_OUT) ? lane : 0;
  float w1[F_IN], w2[F_IN];
  #pragma unroll
  for (int i = 0; i < F_IN; ++i) {
    w1[i] = W1[i * F_OUT + j];
    w2[i] = W2[i * F_OUT + j];
  }
  float bv = bias[j];
  for (int n = wav; n < NNODES; n += nw) {
    const float* Ar = A + (size_t)n * F_IN;
    float acc1 = 0.f, acc2 = 0.f;
    if constexpr (DUAL) {
      #pragma unroll
      for (int i = 0; i < F_IN; ++i) {
        float a = Ar[i];
        acc1 += a * w1[i];
        acc2 += a * w2[i];
      }
    } else {
      const float* Br = B + (size_t)n * F_IN;
      #pragma unroll
      for (int i = 0; i < F_IN; ++i) acc1 += Ar[i] * w1[i] + Br[i] * w2[i];
    }
    if (lane < F_OUT) {
      if constexpr (DUAL) {
        C1[(size_t)n * F_OUT + lane] = acc1;
        C2[(size_t)n * F_OUT + lane] = acc2 + bv;
      } else {
        float r = acc1 + bv;
        if constexpr (RELU) r = fmaxf(r, 0.f);
        C1[(size_t)n * F_OUT + lane] = r;
      }
    }
  }
}

extern "C" void kernel_launch(void* const* d_in, const int* in_sizes, int n_in,
                              void* d_out, int out_size, void* d_ws, size_t ws_size,
                              hipStream_t stream) {
  const uint32_t* xw = (const uint32_t*)d_in[0];
  const uint32_t* ei = (const uint32_t*)d_in[1];

  char* ws = (char*)d_ws;
  size_t off = 0;
  auto carve = [&](size_t bytes) -> char* {
    char* p = ws + off;
    off = (off + bytes + 255) & ~(size_t)255;
    return p;
  };
  int* flags     = (int*)carve(8);
  int* deg       = (int*)carve((size_t)NNODES * 4);
  int* offs      = (int*)carve((size_t)(NNODES + 1) * 4);
  int* cursor    = (int*)carve((size_t)NNODES * 4);
  float* invd    = (float*)carve((size_t)NNODES * 4);
  int* csr       = (int*)carve((size_t)NEDGES * 4);
  float* xf      = (float*)carve((size_t)NNODES * 40 * 4);
  float* wf      = (float*)carve((size_t)32768 * 4);
  float* zf      = (float*)carve((size_t)NNODES * 3 * 4);
  float* b0      = (float*)carve((size_t)NNODES * 64 * 4);
  float* b1      = (float*)carve((size_t)NNODES * 64 * 4);
  float* b2      = (float*)carve((size_t)NNODES * 64 * 4);

  // weight arena layout
  static const int wsz[18] = {2560, 2560, 64, 4096, 4096, 64, 192, 192, 3,
                              192, 192, 64, 4096, 4096, 64, 2560, 2560, 40};
  WPtrs wp;
  int woff = 0;
  for (int i = 0; i < 18; ++i) {
    wp.p[i] = d_in[2 + i];
    wp.sz[i] = wsz[i];
    wp.off[i] = woff;
    woff += wsz[i];
  }
  const float* W[18];
  for (int i = 0; i < 18; ++i) W[i] = wf + wp.off[i];

  void* out = d_out;                                   // x_rec region (N*40)
  char* zout = (char*)d_out;                           // z region starts after x_rec
  // offset in *elements* depends on dtype; compute byte offsets per variant at launch.

  // ---- detect dtypes ----
  detect_k<<<1, 64, 0, stream>>>(xw, ei, flags);

  // ---- CSR build ----
  zero_i32<<<(NNODES + 255) / 256, 256, 0, stream>>>(deg, NNODES);
  hist_k<<<(NEDGES + 255) / 256, 256, 0, stream>>>(ei, deg, flags);
  scan_k<<<1, 1024, 0, stream>>>(deg, offs, cursor, invd, NNODES);
  scatter_k<<<(NEDGES + 255) / 256, 256, 0, stream>>>(ei, cursor, csr, flags);

  // ---- convert inputs to f32 scratch (both variants launched, flag-gated) ----
  const int NX = NNODES * 40;
  cvt_in_k<false><<<(NX + 255) / 256, 256, 0, stream>>>(d_in[0], xf, NX, flags);
  cvt_in_k<true ><<<(NX + 255) / 256, 256, 0, stream>>>(d_in[0], xf, NX, flags);
  cvt_w_k<false><<<18, 256, 0, stream>>>(wp, wf, flags);
  cvt_w_k<true ><<<18, 256, 0, stream>>>(wp, wf, flags);

  const int AGG_BLOCKS = (NNODES * 64) / 256;
  const int GB = 1024;

  // enc1 (40 -> 64)
  agg_k<40, false><<<AGG_BLOCKS, 256, 0, stream>>>(xf, csr, offs, invd, nullptr, b0);
  gemm_k<40, 64, false, true><<<GB, 256, 0, stream>>>(b0, xf, W[0], W[1], W[2], b1, nullptr);
  // enc2 (64 -> 64)
  agg_k<64, false><<<AGG_BLOCKS, 256, 0, stream>>>(b1, csr, offs, invd, nullptr, b0);
  gemm_k<64, 64, false, true><<<GB, 256, 0, stream>>>(b0, b1, W[3], W[4], W[5], b2, nullptr);
  // enc3 (64 -> 3): transform-first
  gemm_k<64, 3, true, false><<<GB, 256, 0, stream>>>(b2, nullptr, W[6], W[7], W[8], b0, b1);
  agg_k<3, true><<<AGG_BLOCKS, 256, 0, stream>>>(b0, csr, offs, invd, b1, zf);
  // dec1 (3 -> 64)
  agg_k<3, false><<<AGG_BLOCKS, 256, 0, stream>>>(zf, csr, offs, invd, nullptr, b0);
  gemm_k<3, 64, false, true><<<GB, 256, 0, stream>>>(b0, zf, W[9], W[10], W[11], b1, nullptr);
  // dec2 (64 -> 64)
  agg_k<64, false><<<AGG_BLOCKS, 256, 0, stream>>>(b1, csr, offs, invd, nullptr, b0);
  gemm_k<64, 64, false, true><<<GB, 256, 0, stream>>>(b0, b1, W[12], W[13], W[14], b2, nullptr);
  // dec3 (64 -> 40): transform-first
  gemm_k<64, 40, true, false><<<GB, 256, 0, stream>>>(b2, nullptr, W[15], W[16], W[17], b0, b1);
  agg_k<40, true><<<AGG_BLOCKS, 256, 0, stream>>>(b0, csr, offs, invd, b1, b2);  // x_rec f32 in b2

  // ---- write outputs in external dtype (flag-gated variants) ----
  const int NZ = NNODES * 3;
  // f32 layout: x_rec at float[0..NX), z at float[NX..NX+NZ)
  cvt_out_k<false><<<(NX + 255) / 256, 256, 0, stream>>>(b2, (float*)d_out, NX, flags);
  cvt_out_k<false><<<(NZ + 255) / 256, 256, 0, stream>>>(zf, (float*)d_out + NX, NZ, flags);
  // bf16 layout: x_rec at bf16[0..NX), z at bf16[NX..NX+NZ)
  cvt_out_k<true ><<<(NX + 255) / 256, 256, 0, stream>>>(b2, (ushort_t*)d_out, NX, flags);
  cvt_out_k<true ><<<(NZ + 255) / 256, 256, 0, stream>>>(zf, (ushort_t*)d_out + NX, NZ, flags);
  (void)out; (void)zout; (void)in_sizes; (void)n_in; (void)out_size; (void)ws_size;
}

// Round 6
// 1177.431 us; speedup vs baseline: 1.0025x; 1.0025x over previous
//
#include <hip/hip_runtime.h>
#include <stdint.h>

#define NNODES 100000
#define NEDGES 1600000

typedef unsigned short ushort_t;

__device__ __forceinline__ float b2f(ushort_t u) {
  union { float f; uint32_t i; } v; v.i = ((uint32_t)u) << 16; return v.f;
}
__device__ __forceinline__ ushort_t f2b(float f) {
  union { float f; uint32_t i; } v; v.f = f;
  uint32_t r = (v.i + 0x7fffu + ((v.i >> 16) & 1u)) >> 16;
  return (ushort_t)r;
}
__device__ __forceinline__ int clampn(int i) {
  return i < 0 ? 0 : (i >= NNODES ? NNODES - 1 : i);
}

// ---- dtype detection (deterministic, once per call) ----
// flags[0] = 1 if float data is bf16, 0 if f32
// flags[1] = 1 if edge_index is int64, 0 if int32
__global__ void detect_k(const uint32_t* __restrict__ x, const uint32_t* __restrict__ ei,
                         int* __restrict__ flags) {
  if (blockIdx.x == 0 && threadIdx.x == 0) {
    int cf = 0, ci = 0;
    for (int i = 0; i < 256; ++i) {
      uint32_t u = x[i];
      uint32_t e = (u >> 7) & 0xFFu;        // exponent field of LOW half viewed as bf16
      if (e >= 100u && e <= 141u) cf++;      // plausible bf16 exponent for ~N(0,1) data
      if (ei[2 * i + 1] == 0u) ci++;         // int64 high words are 0
    }
    flags[0] = (cf >= 128) ? 1 : 0;
    flags[1] = (ci >= 128) ? 1 : 0;
  }
}

__global__ void zero_i32(int* __restrict__ p, int n) {
  int i = blockIdx.x * blockDim.x + threadIdx.x;
  if (i < n) p[i] = 0;
}

__global__ void hist_k(const uint32_t* __restrict__ ei, int* __restrict__ deg,
                       const int* __restrict__ flags) {
  int e = blockIdx.x * blockDim.x + threadIdx.x;
  if (e >= NEDGES) return;
  int i64 = flags[1];
  int d = i64 ? (int)ei[2 * (size_t)NEDGES + 2 * (size_t)e] : (int)ei[(size_t)NEDGES + e];
  atomicAdd(&deg[clampn(d)], 1);
}

__global__ __launch_bounds__(1024) void scan_k(const int* __restrict__ deg, int* __restrict__ offs,
                                               int* __restrict__ cursor, float* __restrict__ invdeg, int n) {
  __shared__ int wsum[16];
  __shared__ int carry_sh;
  int tid = threadIdx.x;
  int lane = tid & 63, wid = tid >> 6;
  if (tid == 0) carry_sh = 0;
  __syncthreads();
  for (int base = 0; base < n; base += 1024) {
    int i = base + tid;
    int v = (i < n) ? deg[i] : 0;
    int s = v;
    #pragma unroll
    for (int d = 1; d < 64; d <<= 1) {
      int t = __shfl_up(s, d);
      if (lane >= d) s += t;
    }
    __syncthreads();               // protect wsum from previous iteration reads
    if (lane == 63) wsum[wid] = s;
    __syncthreads();
    int wprefix = 0, total = 0;
    #pragma unroll
    for (int w = 0; w < 16; ++w) {
      int ws_ = wsum[w];
      if (w < wid) wprefix += ws_;
      total += ws_;
    }
    int carry = carry_sh;
    if (i < n) {
      int excl = carry + wprefix + s - v;
      offs[i] = excl;
      cursor[i] = excl;
      invdeg[i] = 1.0f / fmaxf((float)v, 1.0f);
    }
    __syncthreads();
    if (tid == 0) carry_sh = carry + total;
  }
  __syncthreads();
  if (tid == 0) offs[n] = carry_sh;
}

__global__ void scatter_k(const uint32_t* __restrict__ ei, int* __restrict__ cursor,
                          int* __restrict__ csr, const int* __restrict__ flags) {
  int e = blockIdx.x * blockDim.x + threadIdx.x;
  if (e >= NEDGES) return;
  int i64 = flags[1];
  int s, d;
  if (i64) {
    s = (int)ei[2 * (size_t)e];
    d = (int)ei[2 * (size_t)NEDGES + 2 * (size_t)e];
  } else {
    s = (int)ei[e];
    d = (int)ei[(size_t)NEDGES + e];
  }
  int p = atomicAdd(&cursor[clampn(d)], 1);
  if (p >= 0 && p < NEDGES) csr[p] = clampn(s);
}

// ---- dtype-gated conversion kernels ----
template <bool BF16>
__global__ void cvt_in_k(const void* __restrict__ src, float* __restrict__ dst, int n,
                         const int* __restrict__ flags) {
  if (flags[0] != (BF16 ? 1 : 0)) return;
  int i = blockIdx.x * blockDim.x + threadIdx.x;
  if (i < n) dst[i] = BF16 ? b2f(((const ushort_t*)src)[i]) : ((const float*)src)[i];
}

template <bool BF16>
__global__ void cvt_out_k(const float* __restrict__ src, void* __restrict__ dst, int n,
                          const int* __restrict__ flags) {
  if (flags[0] != (BF16 ? 1 : 0)) return;
  int i = blockIdx.x * blockDim.x + threadIdx.x;
  if (i < n) {
    if constexpr (BF16) ((ushort_t*)dst)[i] = f2b(src[i]);
    else ((float*)dst)[i] = src[i];
  }
}

struct WPtrs { const void* p[18]; int sz[18]; int off[18]; };

template <bool BF16>
__global__ void cvt_w_k(WPtrs w, float* __restrict__ dst, const int* __restrict__ flags) {
  if (flags[0] != (BF16 ? 1 : 0)) return;
  int a = blockIdx.x;
  int sz = w.sz[a], off = w.off[a];
  for (int t = threadIdx.x; t < sz; t += blockDim.x) {
    dst[off + t] = BF16 ? b2f(((const ushort_t*)w.p[a])[t]) : ((const float*)w.p[a])[t];
  }
}

// ---- f32 pipeline: one wave per destination node; lane = feature ----
template <int F, bool ADD_U>
__global__ __launch_bounds__(256) void agg_k(const float* __restrict__ feat, const int* __restrict__ csr,
                                             const int* __restrict__ offs, const float* __restrict__ invdeg,
                                             const float* __restrict__ u, float* __restrict__ out) {
  int lane = threadIdx.x & 63;
  int n = (blockIdx.x * blockDim.x + threadIdx.x) >> 6;
  if (n >= NNODES) return;
  int k0 = offs[n], k1 = offs[n + 1];
  float acc = 0.f;
  int k = k0;
  for (; k + 4 <= k1; k += 4) {
    int n0 = csr[k], n1 = csr[k + 1], n2 = csr[k + 2], n3 = csr[k + 3];
    if (lane < F) {
      acc += feat[(size_t)n0 * F + lane];
      acc += feat[(size_t)n1 * F + lane];
      acc += feat[(size_t)n2 * F + lane];
      acc += feat[(size_t)n3 * F + lane];
    }
  }
  for (; k < k1; ++k) {
    int nn = csr[k];
    if (lane < F) acc += feat[(size_t)nn * F + lane];
  }
  if (lane < F) {
    float val = acc * invdeg[n];
    if constexpr (ADD_U) val += u[(size_t)n * F + lane];
    out[(size_t)n * F + lane] = val;
  }
}

// One wave per node; lane = output column; weight columns in VGPRs.
// DUAL=false: C1 = act(A@W1 + B@W2 + bias)
// DUAL=true : C1 = A@W1 ; C2 = A@W2 + bias
template <int F_IN, int F_OUT, bool DUAL, bool RELU>
__global__ __launch_bounds__(256) void gemm_k(const float* __restrict__ A, const float* __restrict__ B,
                                              const float* __restrict__ W1, const float* __restrict__ W2,
                                              const float* __restrict__ bias,
                                              float* __restrict__ C1, float* __restrict__ C2) {
  int lane = threadIdx.x & 63;
  int wav = (blockIdx.x * blockDim.x + threadIdx.x) >> 6;
  int nw = (gridDim.x * blockDim.x) >> 6;
  int j = (lane < F_OUT) ? lane : 0;
  float w1[F_IN], w2[F_IN];
  #pragma unroll
  for (int i = 0; i < F_IN; ++i) {
    w1[i] = W1[i * F_OUT + j];
    w2[i] = W2[i * F_OUT + j];
  }
  float bv = bias[j];
  for (int n = wav; n < NNODES; n += nw) {
    const float* Ar = A + (size_t)n * F_IN;
    float acc1 = 0.f, acc2 = 0.f;
    if constexpr (DUAL) {
      #pragma unroll
      for (int i = 0; i < F_IN; ++i) {
        float a = Ar[i];
        acc1 += a * w1[i];
        acc2 += a * w2[i];
      }
    } else {
      const float* Br = B + (size_t)n * F_IN;
      #pragma unroll
      for (int i = 0; i < F_IN; ++i) acc1 += Ar[i] * w1[i] + Br[i] * w2[i];
    }
    if (lane < F_OUT) {
      if constexpr (DUAL) {
        C1[(size_t)n * F_OUT + lane] = acc1;
        C2[(size_t)n * F_OUT + lane] = acc2 + bv;
      } else {
        float r = acc1 + bv;
        if constexpr (RELU) r = fmaxf(r, 0.f);
        C1[(size_t)n * F_OUT + lane] = r;
      }
    }
  }
}

extern "C" void kernel_launch(void* const* d_in, const int* in_sizes, int n_in,
                              void* d_out, int out_size, void* d_ws, size_t ws_size,
                              hipStream_t stream) {
  const uint32_t* xw = (const uint32_t*)d_in[0];
  const uint32_t* ei = (const uint32_t*)d_in[1];

  char* ws = (char*)d_ws;
  size_t off = 0;
  auto carve = [&](size_t bytes) -> char* {
    char* p = ws + off;
    off = (off + bytes + 255) & ~(size_t)255;
    return p;
  };
  int* flags     = (int*)carve(8);
  int* deg       = (int*)carve((size_t)NNODES * 4);
  int* offs      = (int*)carve((size_t)(NNODES + 1) * 4);
  int* cursor    = (int*)carve((size_t)NNODES * 4);
  float* invd    = (float*)carve((size_t)NNODES * 4);
  int* csr       = (int*)carve((size_t)NEDGES * 4);
  float* xf      = (float*)carve((size_t)NNODES * 40 * 4);
  float* wf      = (float*)carve((size_t)32768 * 4);
  float* zf      = (float*)carve((size_t)NNODES * 3 * 4);
  float* b0      = (float*)carve((size_t)NNODES * 64 * 4);
  float* b1      = (float*)carve((size_t)NNODES * 64 * 4);
  float* b2      = (float*)carve((size_t)NNODES * 64 * 4);

  // weight arena layout
  static const int wsz[18] = {2560, 2560, 64, 4096, 4096, 64, 192, 192, 3,
                              192, 192, 64, 4096, 4096, 64, 2560, 2560, 40};
  WPtrs wp;
  int woff = 0;
  for (int i = 0; i < 18; ++i) {
    wp.p[i] = d_in[2 + i];
    wp.sz[i] = wsz[i];
    wp.off[i] = woff;
    woff += wsz[i];
  }
  const float* W[18];
  for (int i = 0; i < 18; ++i) W[i] = wf + wp.off[i];

  void* out = d_out;                                   // x_rec region (N*40)
  char* zout = (char*)d_out;                           // z region starts after x_rec
  // offset in *elements* depends on dtype; compute byte offsets per variant at launch.

  // ---- detect dtypes ----
  detect_k<<<1, 64, 0, stream>>>(xw, ei, flags);

  // ---- CSR build ----
  zero_i32<<<(NNODES + 255) / 256, 256, 0, stream>>>(deg, NNODES);
  hist_k<<<(NEDGES + 255) / 256, 256, 0, stream>>>(ei, deg, flags);
  scan_k<<<1, 1024, 0, stream>>>(deg, offs, cursor, invd, NNODES);
  scatter_k<<<(NEDGES + 255) / 256, 256, 0, stream>>>(ei, cursor, csr, flags);

  // ---- convert inputs to f32 scratch (both variants launched, flag-gated) ----
  const int NX = NNODES * 40;
  cvt_in_k<false><<<(NX + 255) / 256, 256, 0, stream>>>(d_in[0], xf, NX, flags);
  cvt_in_k<true ><<<(NX + 255) / 256, 256, 0, stream>>>(d_in[0], xf, NX, flags);
  cvt_w_k<false><<<18, 256, 0, stream>>>(wp, wf, flags);
  cvt_w_k<true ><<<18, 256, 0, stream>>>(wp, wf, flags);

  const int AGG_BLOCKS = (NNODES * 64) / 256;
  const int GB = 1024;

  // enc1 (40 -> 64)
  agg_k<40, false><<<AGG_BLOCKS, 256, 0, stream>>>(xf, csr, offs, invd, nullptr, b0);
  gemm_k<40, 64, false, true><<<GB, 256, 0, stream>>>(b0, xf, W[0], W[1], W[2], b1, nullptr);
  // enc2 (64 -> 64)
  agg_k<64, false><<<AGG_BLOCKS, 256, 0, stream>>>(b1, csr, offs, invd, nullptr, b0);
  gemm_k<64, 64, false, true><<<GB, 256, 0, stream>>>(b0, b1, W[3], W[4], W[5], b2, nullptr);
  // enc3 (64 -> 3): transform-first
  gemm_k<64, 3, true, false><<<GB, 256, 0, stream>>>(b2, nullptr, W[6], W[7], W[8], b0, b1);
  agg_k<3, true><<<AGG_BLOCKS, 256, 0, stream>>>(b0, csr, offs, invd, b1, zf);
  // dec1 (3 -> 64)
  agg_k<3, false><<<AGG_BLOCKS, 256, 0, stream>>>(zf, csr, offs, invd, nullptr, b0);
  gemm_k<3, 64, false, true><<<GB, 256, 0, stream>>>(b0, zf, W[9], W[10], W[11], b1, nullptr);
  // dec2 (64 -> 64)
  agg_k<64, false><<<AGG_BLOCKS, 256, 0, stream>>>(b1, csr, offs, invd, nullptr, b0);
  gemm_k<64, 64, false, true><<<GB, 256, 0, stream>>>(b0, b1, W[12], W[13], W[14], b2, nullptr);
  // dec3 (64 -> 40): transform-first
  gemm_k<64, 40, true, false><<<GB, 256, 0, stream>>>(b2, nullptr, W[15], W[16], W[17], b0, b1);
  agg_k<40, true><<<AGG_BLOCKS, 256, 0, stream>>>(b0, csr, offs, invd, b1, b2);  // x_rec f32 in b2

  // ---- write outputs in external dtype (flag-gated variants) ----
  const int NZ = NNODES * 3;
  // f32 layout: x_rec at float[0..NX), z at float[NX..NX+NZ)
  cvt_out_k<false><<<(NX + 255) / 256, 256, 0, stream>>>(b2, (float*)d_out, NX, flags);
  cvt_out_k<false><<<(NZ + 255) / 256, 256, 0, stream>>>(zf, (float*)d_out + NX, NZ, flags);
  // bf16 layout: x_rec at bf16[0..NX), z at bf16[NX..NX+NZ)
  cvt_out_k<true ><<<(NX + 255) / 256, 256, 0, stream>>>(b2, (ushort_t*)d_out, NX, flags);
  cvt_out_k<true ><<<(NZ + 255) / 256, 256, 0, stream>>>(zf, (ushort_t*)d_out + NX, NZ, flags);
  (void)out; (void)zout; (void)in_sizes; (void)n_in; (void)out_size; (void)ws_size;
}

// Round 7
// 1073.837 us; speedup vs baseline: 1.0992x; 1.0965x over previous
//
#include <hip/hip_runtime.h>
#include <stdint.h>

#define NNODES 100000
#define NEDGES 1600000

typedef unsigned short ushort_t;

__device__ __forceinline__ float b2f(ushort_t u) {
  union { float f; uint32_t i; } v; v.i = ((uint32_t)u) << 16; return v.f;
}
__device__ __forceinline__ ushort_t f2b(float f) {
  union { float f; uint32_t i; } v; v.f = f;
  uint32_t r = (v.i + 0x7fffu + ((v.i >> 16) & 1u)) >> 16;
  return (ushort_t)r;
}
__device__ __forceinline__ int clampn(int i) {
  return i < 0 ? 0 : (i >= NNODES ? NNODES - 1 : i);
}

// ---- dtype detection (deterministic, once per call) ----
// flags[0] = 1 if float data is bf16, 0 if f32
// flags[1] = 1 if edge_index is int64, 0 if int32
__global__ void detect_k(const uint32_t* __restrict__ x, const uint32_t* __restrict__ ei,
                         int* __restrict__ flags) {
  if (blockIdx.x == 0 && threadIdx.x == 0) {
    int cf = 0, ci = 0;
    for (int i = 0; i < 256; ++i) {
      uint32_t u = x[i];
      uint32_t e = (u >> 7) & 0xFFu;
      if (e >= 100u && e <= 141u) cf++;
      if (ei[2 * i + 1] == 0u) ci++;
    }
    flags[0] = (cf >= 128) ? 1 : 0;
    flags[1] = (ci >= 128) ? 1 : 0;
  }
}

__global__ void zero_i32(int* __restrict__ p, int n) {
  int i = blockIdx.x * blockDim.x + threadIdx.x;
  if (i < n) p[i] = 0;
}

__global__ void hist_k(const uint32_t* __restrict__ ei, int* __restrict__ deg,
                       const int* __restrict__ flags) {
  int e = blockIdx.x * blockDim.x + threadIdx.x;
  if (e >= NEDGES) return;
  int i64 = flags[1];
  int d = i64 ? (int)ei[2 * (size_t)NEDGES + 2 * (size_t)e] : (int)ei[(size_t)NEDGES + e];
  atomicAdd(&deg[clampn(d)], 1);
}

__global__ __launch_bounds__(1024) void scan_k(const int* __restrict__ deg, int* __restrict__ offs,
                                               int* __restrict__ cursor, float* __restrict__ invdeg, int n) {
  __shared__ int wsum[16];
  __shared__ int carry_sh;
  int tid = threadIdx.x;
  int lane = tid & 63, wid = tid >> 6;
  if (tid == 0) carry_sh = 0;
  __syncthreads();
  for (int base = 0; base < n; base += 1024) {
    int i = base + tid;
    int v = (i < n) ? deg[i] : 0;
    int s = v;
    #pragma unroll
    for (int d = 1; d < 64; d <<= 1) {
      int t = __shfl_up(s, d);
      if (lane >= d) s += t;
    }
    __syncthreads();
    if (lane == 63) wsum[wid] = s;
    __syncthreads();
    int wprefix = 0, total = 0;
    #pragma unroll
    for (int w = 0; w < 16; ++w) {
      int ws_ = wsum[w];
      if (w < wid) wprefix += ws_;
      total += ws_;
    }
    int carry = carry_sh;
    if (i < n) {
      int excl = carry + wprefix + s - v;
      offs[i] = excl;
      cursor[i] = excl;
      invdeg[i] = 1.0f / fmaxf((float)v, 1.0f);
    }
    __syncthreads();
    if (tid == 0) carry_sh = carry + total;
  }
  __syncthreads();
  if (tid == 0) offs[n] = carry_sh;
}

__global__ void scatter_k(const uint32_t* __restrict__ ei, int* __restrict__ cursor,
                          int* __restrict__ csr, const int* __restrict__ flags) {
  int e = blockIdx.x * blockDim.x + threadIdx.x;
  if (e >= NEDGES) return;
  int i64 = flags[1];
  int s, d;
  if (i64) {
    s = (int)ei[2 * (size_t)e];
    d = (int)ei[2 * (size_t)NEDGES + 2 * (size_t)e];
  } else {
    s = (int)ei[e];
    d = (int)ei[(size_t)NEDGES + e];
  }
  int p = atomicAdd(&cursor[clampn(d)], 1);
  if (p >= 0 && p < NEDGES) csr[p] = clampn(s);
}

// ---- dtype-gated conversion kernels ----
template <bool BF16>
__global__ void cvt_in_k(const void* __restrict__ src, float* __restrict__ dst, int n,
                         const int* __restrict__ flags) {
  if (flags[0] != (BF16 ? 1 : 0)) return;
  int i = blockIdx.x * blockDim.x + threadIdx.x;
  if (i < n) dst[i] = BF16 ? b2f(((const ushort_t*)src)[i]) : ((const float*)src)[i];
}

template <bool BF16>
__global__ void cvt_out_k(const float* __restrict__ src, void* __restrict__ dst, int n,
                          const int* __restrict__ flags) {
  if (flags[0] != (BF16 ? 1 : 0)) return;
  int i = blockIdx.x * blockDim.x + threadIdx.x;
  if (i < n) {
    if constexpr (BF16) ((ushort_t*)dst)[i] = f2b(src[i]);
    else ((float*)dst)[i] = src[i];
  }
}

struct WPtrs { const void* p[18]; int sz[18]; int off[18]; };

template <bool BF16>
__global__ void cvt_w_k(WPtrs w, float* __restrict__ dst, const int* __restrict__ flags) {
  if (flags[0] != (BF16 ? 1 : 0)) return;
  int a = blockIdx.x;
  int sz = w.sz[a], off = w.off[a];
  for (int t = threadIdx.x; t < sz; t += blockDim.x) {
    dst[off + t] = BF16 ? b2f(((const ushort_t*)w.p[a])[t]) : ((const float*)w.p[a])[t];
  }
}

// ---- f32 pipeline: one wave per destination node; lane = feature ----
template <int F, bool ADD_U>
__global__ __launch_bounds__(256) void agg_k(const float* __restrict__ feat, const int* __restrict__ csr,
                                             const int* __restrict__ offs, const float* __restrict__ invdeg,
                                             const float* __restrict__ u, float* __restrict__ out) {
  int lane = threadIdx.x & 63;
  int n = (blockIdx.x * blockDim.x + threadIdx.x) >> 6;
  if (n >= NNODES) return;
  int k0 = offs[n], k1 = offs[n + 1];
  float acc = 0.f;
  int k = k0;
  for (; k + 4 <= k1; k += 4) {
    int n0 = csr[k], n1 = csr[k + 1], n2 = csr[k + 2], n3 = csr[k + 3];
    if (lane < F) {
      acc += feat[(size_t)n0 * F + lane];
      acc += feat[(size_t)n1 * F + lane];
      acc += feat[(size_t)n2 * F + lane];
      acc += feat[(size_t)n3 * F + lane];
    }
  }
  for (; k < k1; ++k) {
    int nn = csr[k];
    if (lane < F) acc += feat[(size_t)nn * F + lane];
  }
  if (lane < F) {
    float val = acc * invdeg[n];
    if constexpr (ADD_U) val += u[(size_t)n * F + lane];
    out[(size_t)n * F + lane] = val;
  }
}

// ---- LDS-tiled fused linear: one block per 64-node tile ----
// DUAL=false: C1 = act(A@W1 + B@W2 + bias)
// DUAL=true : C1 = A@W1 ; C2 = A@W2 + bias
template <int F_IN, int F_OUT, bool DUAL, bool RELU>
__global__ __launch_bounds__(256) void gemm2_k(const float* __restrict__ A, const float* __restrict__ B,
                                               const float* __restrict__ W1, const float* __restrict__ W2,
                                               const float* __restrict__ bias,
                                               float* __restrict__ C1, float* __restrict__ C2) {
  constexpr int TILE = 64;
  constexpr int JP = (F_OUT <= 4) ? 4 : 64;   // j-slots per node
  constexpr int NG = 256 / JP;                // node-groups per block
  __shared__ alignas(16) float sA[TILE][F_IN];
  __shared__ alignas(16) float sB[DUAL ? 1 : TILE][DUAL ? 1 : F_IN];
  int tid = threadIdx.x;
  int tile0 = blockIdx.x * TILE;
  int valid = NNODES - tile0;
  if (valid > TILE) valid = TILE;
  // stage tiles (coalesced global reads, linear LDS writes)
  for (int e = tid; e < valid * F_IN; e += 256) {
    int r = e / F_IN, c = e - r * F_IN;
    sA[r][c] = A[(size_t)tile0 * F_IN + e];
    if constexpr (!DUAL) sB[r][c] = B[(size_t)tile0 * F_IN + e];
  }
  __syncthreads();
  int j = tid % JP;
  int jj = (j < F_OUT) ? j : F_OUT - 1;   // clamp so weight reads stay in-bounds
  int g = tid / JP;
  float w1[F_IN], w2[F_IN];
  #pragma unroll
  for (int i = 0; i < F_IN; ++i) {
    w1[i] = W1[i * F_OUT + jj];
    w2[i] = W2[i * F_OUT + jj];
  }
  float bv = bias[jj];
  for (int nl = g; nl < valid; nl += NG) {
    float acc1 = 0.f, acc2 = 0.f;
    if constexpr ((F_IN & 3) == 0) {
      const float4* a4 = (const float4*)sA[nl];
      #pragma unroll
      for (int i4 = 0; i4 < F_IN / 4; ++i4) {
        float4 v = a4[i4];
        acc1 += v.x * w1[4 * i4] + v.y * w1[4 * i4 + 1] + v.z * w1[4 * i4 + 2] + v.w * w1[4 * i4 + 3];
        if constexpr (DUAL)
          acc2 += v.x * w2[4 * i4] + v.y * w2[4 * i4 + 1] + v.z * w2[4 * i4 + 2] + v.w * w2[4 * i4 + 3];
      }
      if constexpr (!DUAL) {
        const float4* b4 = (const float4*)sB[nl];
        #pragma unroll
        for (int i4 = 0; i4 < F_IN / 4; ++i4) {
          float4 v = b4[i4];
          acc1 += v.x * w2[4 * i4] + v.y * w2[4 * i4 + 1] + v.z * w2[4 * i4 + 2] + v.w * w2[4 * i4 + 3];
        }
      }
    } else {
      #pragma unroll
      for (int i = 0; i < F_IN; ++i) {
        acc1 += sA[nl][i] * w1[i];
        if constexpr (DUAL) acc2 += sA[nl][i] * w2[i];
        else acc1 += sB[nl][i] * w2[i];
      }
    }
    if (j < F_OUT) {
      size_t o = (size_t)(tile0 + nl) * F_OUT + j;
      if constexpr (DUAL) {
        C1[o] = acc1;
        C2[o] = acc2 + bv;
      } else {
        float r = acc1 + bv;
        if constexpr (RELU) r = fmaxf(r, 0.f);
        C1[o] = r;
      }
    }
  }
}

extern "C" void kernel_launch(void* const* d_in, const int* in_sizes, int n_in,
                              void* d_out, int out_size, void* d_ws, size_t ws_size,
                              hipStream_t stream) {
  const uint32_t* xw = (const uint32_t*)d_in[0];
  const uint32_t* ei = (const uint32_t*)d_in[1];

  char* ws = (char*)d_ws;
  size_t off = 0;
  auto carve = [&](size_t bytes) -> char* {
    char* p = ws + off;
    off = (off + bytes + 255) & ~(size_t)255;
    return p;
  };
  int* flags     = (int*)carve(8);
  int* deg       = (int*)carve((size_t)NNODES * 4);
  int* offs      = (int*)carve((size_t)(NNODES + 1) * 4);
  int* cursor    = (int*)carve((size_t)NNODES * 4);
  float* invd    = (float*)carve((size_t)NNODES * 4);
  int* csr       = (int*)carve((size_t)NEDGES * 4);
  float* xf      = (float*)carve((size_t)NNODES * 40 * 4);
  float* wf      = (float*)carve((size_t)32768 * 4);
  float* zf      = (float*)carve((size_t)NNODES * 3 * 4);
  float* b0      = (float*)carve((size_t)NNODES * 64 * 4);
  float* b1      = (float*)carve((size_t)NNODES * 64 * 4);
  float* b2      = (float*)carve((size_t)NNODES * 64 * 4);

  static const int wsz[18] = {2560, 2560, 64, 4096, 4096, 64, 192, 192, 3,
                              192, 192, 64, 4096, 4096, 64, 2560, 2560, 40};
  WPtrs wp;
  int woff = 0;
  for (int i = 0; i < 18; ++i) {
    wp.p[i] = d_in[2 + i];
    wp.sz[i] = wsz[i];
    wp.off[i] = woff;
    woff += wsz[i];
  }
  const float* W[18];
  for (int i = 0; i < 18; ++i) W[i] = wf + wp.off[i];

  // ---- detect dtypes ----
  detect_k<<<1, 64, 0, stream>>>(xw, ei, flags);

  // ---- CSR build ----
  zero_i32<<<(NNODES + 255) / 256, 256, 0, stream>>>(deg, NNODES);
  hist_k<<<(NEDGES + 255) / 256, 256, 0, stream>>>(ei, deg, flags);
  scan_k<<<1, 1024, 0, stream>>>(deg, offs, cursor, invd, NNODES);
  scatter_k<<<(NEDGES + 255) / 256, 256, 0, stream>>>(ei, cursor, csr, flags);

  // ---- convert inputs to f32 scratch (both variants launched, flag-gated) ----
  const int NX = NNODES * 40;
  cvt_in_k<false><<<(NX + 255) / 256, 256, 0, stream>>>(d_in[0], xf, NX, flags);
  cvt_in_k<true ><<<(NX + 255) / 256, 256, 0, stream>>>(d_in[0], xf, NX, flags);
  cvt_w_k<false><<<18, 256, 0, stream>>>(wp, wf, flags);
  cvt_w_k<true ><<<18, 256, 0, stream>>>(wp, wf, flags);

  const int AGG_BLOCKS = (NNODES * 64) / 256;
  const int NTILES = (NNODES + 63) / 64;   // 1563

  // enc1 (40 -> 64)
  agg_k<40, false><<<AGG_BLOCKS, 256, 0, stream>>>(xf, csr, offs, invd, nullptr, b0);
  gemm2_k<40, 64, false, true><<<NTILES, 256, 0, stream>>>(b0, xf, W[0], W[1], W[2], b1, nullptr);
  // enc2 (64 -> 64)
  agg_k<64, false><<<AGG_BLOCKS, 256, 0, stream>>>(b1, csr, offs, invd, nullptr, b0);
  gemm2_k<64, 64, false, true><<<NTILES, 256, 0, stream>>>(b0, b1, W[3], W[4], W[5], b2, nullptr);
  // enc3 (64 -> 3): transform-first
  gemm2_k<64, 3, true, false><<<NTILES, 256, 0, stream>>>(b2, nullptr, W[6], W[7], W[8], b0, b1);
  agg_k<3, true><<<AGG_BLOCKS, 256, 0, stream>>>(b0, csr, offs, invd, b1, zf);
  // dec1 (3 -> 64)
  agg_k<3, false><<<AGG_BLOCKS, 256, 0, stream>>>(zf, csr, offs, invd, nullptr, b0);
  gemm2_k<3, 64, false, true><<<NTILES, 256, 0, stream>>>(b0, zf, W[9], W[10], W[11], b1, nullptr);
  // dec2 (64 -> 64)
  agg_k<64, false><<<AGG_BLOCKS, 256, 0, stream>>>(b1, csr, offs, invd, nullptr, b0);
  gemm2_k<64, 64, false, true><<<NTILES, 256, 0, stream>>>(b0, b1, W[12], W[13], W[14], b2, nullptr);
  // dec3 (64 -> 40): transform-first
  gemm2_k<64, 40, true, false><<<NTILES, 256, 0, stream>>>(b2, nullptr, W[15], W[16], W[17], b0, b1);
  agg_k<40, true><<<AGG_BLOCKS, 256, 0, stream>>>(b0, csr, offs, invd, b1, b2);  // x_rec f32 in b2

  // ---- write outputs in external dtype (flag-gated variants) ----
  const int NZ = NNODES * 3;
  cvt_out_k<false><<<(NX + 255) / 256, 256, 0, stream>>>(b2, (float*)d_out, NX, flags);
  cvt_out_k<false><<<(NZ + 255) / 256, 256, 0, stream>>>(zf, (float*)d_out + NX, NZ, flags);
  cvt_out_k<true ><<<(NX + 255) / 256, 256, 0, stream>>>(b2, (ushort_t*)d_out, NX, flags);
  cvt_out_k<true ><<<(NZ + 255) / 256, 256, 0, stream>>>(zf, (ushort_t*)d_out + NX, NZ, flags);
  (void)in_sizes; (void)n_in; (void)out_size; (void)ws_size;
}

// Round 9
// 842.999 us; speedup vs baseline: 1.4003x; 1.2738x over previous
//
#include <hip/hip_runtime.h>
#include <stdint.h>

#define NNODES 100000
#define NEDGES 1600000

typedef unsigned short ushort_t;
typedef __attribute__((ext_vector_type(8))) short bf16x8;
typedef __attribute__((ext_vector_type(4))) float f32x4;

__device__ __forceinline__ float b2f(ushort_t u) {
  union { float f; uint32_t i; } v; v.i = ((uint32_t)u) << 16; return v.f;
}
__device__ __forceinline__ ushort_t f2b(float f) {
  union { float f; uint32_t i; } v; v.f = f;
  uint32_t r = (v.i + 0x7fffu + ((v.i >> 16) & 1u)) >> 16;
  return (ushort_t)r;
}
__device__ __forceinline__ int clampn(int i) {
  return i < 0 ? 0 : (i >= NNODES ? NNODES - 1 : i);
}

// ---- dtype detection (deterministic, once per call) ----
__global__ void detect_k(const uint32_t* __restrict__ x, const uint32_t* __restrict__ ei,
                         int* __restrict__ flags) {
  if (blockIdx.x == 0 && threadIdx.x == 0) {
    int cf = 0, ci = 0;
    for (int i = 0; i < 256; ++i) {
      uint32_t u = x[i];
      uint32_t e = (u >> 7) & 0xFFu;
      if (e >= 100u && e <= 141u) cf++;
      if (ei[2 * i + 1] == 0u) ci++;
    }
    flags[0] = (cf >= 128) ? 1 : 0;
    flags[1] = (ci >= 128) ? 1 : 0;
  }
}

__global__ void zero_i32(int* __restrict__ p, int n) {
  int i = blockIdx.x * blockDim.x + threadIdx.x;
  if (i < n) p[i] = 0;
}

__global__ void hist_k(const uint32_t* __restrict__ ei, int* __restrict__ deg,
                       const int* __restrict__ flags) {
  int e = blockIdx.x * blockDim.x + threadIdx.x;
  if (e >= NEDGES) return;
  int i64 = flags[1];
  int d = i64 ? (int)ei[2 * (size_t)NEDGES + 2 * (size_t)e] : (int)ei[(size_t)NEDGES + e];
  atomicAdd(&deg[clampn(d)], 1);
}

__global__ __launch_bounds__(1024) void scan_k(const int* __restrict__ deg, int* __restrict__ offs,
                                               int* __restrict__ cursor, float* __restrict__ invdeg, int n) {
  __shared__ int wsum[16];
  __shared__ int carry_sh;
  int tid = threadIdx.x;
  int lane = tid & 63, wid = tid >> 6;
  if (tid == 0) carry_sh = 0;
  __syncthreads();
  for (int base = 0; base < n; base += 1024) {
    int i = base + tid;
    int v = (i < n) ? deg[i] : 0;
    int s = v;
    #pragma unroll
    for (int d = 1; d < 64; d <<= 1) {
      int t = __shfl_up(s, d);
      if (lane >= d) s += t;
    }
    __syncthreads();
    if (lane == 63) wsum[wid] = s;
    __syncthreads();
    int wprefix = 0, total = 0;
    #pragma unroll
    for (int w = 0; w < 16; ++w) {
      int ws_ = wsum[w];
      if (w < wid) wprefix += ws_;
      total += ws_;
    }
    int carry = carry_sh;
    if (i < n) {
      int excl = carry + wprefix + s - v;
      offs[i] = excl;
      cursor[i] = excl;
      invdeg[i] = 1.0f / fmaxf((float)v, 1.0f);
    }
    __syncthreads();
    if (tid == 0) carry_sh = carry + total;
  }
  __syncthreads();
  if (tid == 0) offs[n] = carry_sh;
}

__global__ void scatter_k(const uint32_t* __restrict__ ei, int* __restrict__ cursor,
                          int* __restrict__ csr, const int* __restrict__ flags) {
  int e = blockIdx.x * blockDim.x + threadIdx.x;
  if (e >= NEDGES) return;
  int i64 = flags[1];
  int s, d;
  if (i64) {
    s = (int)ei[2 * (size_t)e];
    d = (int)ei[2 * (size_t)NEDGES + 2 * (size_t)e];
  } else {
    s = (int)ei[e];
    d = (int)ei[(size_t)NEDGES + e];
  }
  int p = atomicAdd(&cursor[clampn(d)], 1);
  if (p >= 0 && p < NEDGES) csr[p] = clampn(s);
}

// ---- dtype-gated conversion kernels (proven) ----
template <bool BF16>
__global__ void cvt_in_k(const void* __restrict__ src, float* __restrict__ dst, int n,
                         const int* __restrict__ flags) {
  if (flags[0] != (BF16 ? 1 : 0)) return;
  int i = blockIdx.x * blockDim.x + threadIdx.x;
  if (i < n) dst[i] = BF16 ? b2f(((const ushort_t*)src)[i]) : ((const float*)src)[i];
}

template <bool BF16>
__global__ void cvt_out_k(const float* __restrict__ src, void* __restrict__ dst, int n,
                          const int* __restrict__ flags) {
  if (flags[0] != (BF16 ? 1 : 0)) return;
  int i = blockIdx.x * blockDim.x + threadIdx.x;
  if (i < n) {
    if constexpr (BF16) ((ushort_t*)dst)[i] = f2b(src[i]);
    else ((float*)dst)[i] = src[i];
  }
}

struct WPtrs { const void* p[18]; int sz[18]; int off[18]; };

template <bool BF16>
__global__ void cvt_w_k(WPtrs w, float* __restrict__ dst, const int* __restrict__ flags) {
  if (flags[0] != (BF16 ? 1 : 0)) return;
  int a = blockIdx.x;
  int sz = w.sz[a], off = w.off[a];
  for (int t = threadIdx.x; t < sz; t += blockDim.x) {
    dst[off + t] = BF16 ? b2f(((const ushort_t*)w.p[a])[t]) : ((const float*)w.p[a])[t];
  }
}

// ---- f32 aggregation: one wave per destination node; lane = feature (proven) ----
template <int F, bool ADD_U>
__global__ __launch_bounds__(256) void agg_k(const float* __restrict__ feat, const int* __restrict__ csr,
                                             const int* __restrict__ offs, const float* __restrict__ invdeg,
                                             const float* __restrict__ u, float* __restrict__ out) {
  int lane = threadIdx.x & 63;
  int n = (blockIdx.x * blockDim.x + threadIdx.x) >> 6;
  if (n >= NNODES) return;
  int k0 = offs[n], k1 = offs[n + 1];
  float acc = 0.f;
  int k = k0;
  for (; k + 4 <= k1; k += 4) {
    int n0 = csr[k], n1 = csr[k + 1], n2 = csr[k + 2], n3 = csr[k + 3];
    if (lane < F) {
      acc += feat[(size_t)n0 * F + lane];
      acc += feat[(size_t)n1 * F + lane];
      acc += feat[(size_t)n2 * F + lane];
      acc += feat[(size_t)n3 * F + lane];
    }
  }
  for (; k < k1; ++k) {
    int nn = csr[k];
    if (lane < F) acc += feat[(size_t)nn * F + lane];
  }
  if (lane < F) {
    float val = acc * invdeg[n];
    if constexpr (ADD_U) val += u[(size_t)n * F + lane];
    out[(size_t)n * F + lane] = val;
  }
}

// ---- MFMA fused linear: one wave per 16-node tile, all F_OUT columns ----
// ALL operands from f32 buffers (A,B scratch; W1,W2,Wb from f32 weight arena),
// converted to bf16 in-register via proven f2b. No direct ushort loads here.
// DUAL=false: C1 = act(A@W1 + B@W2 + bias) ; DUAL=true: C1 = A@W1 ; C2 = A@W2 + bias
// Fragments: A[m=lane&15][k=(lane>>4)*8+j], B[k=(lane>>4)*8+j][n=lane&15],
// D: col=lane&15, row=(lane>>4)*4+reg (m89-verified). Any consistent k-permutation cancels.
template <int F_IN, int F_OUT, bool DUAL, bool RELU>
__global__ __launch_bounds__(256) void mgemm_k(const float* __restrict__ A, const float* __restrict__ B,
                                               const float* __restrict__ W1, const float* __restrict__ W2,
                                               const float* __restrict__ Wb,
                                               float* __restrict__ C1, float* __restrict__ C2) {
  constexpr int KS = (F_IN + 31) / 32;
  constexpr int JT = (F_OUT + 15) / 16;
  int lane = threadIdx.x & 63;
  int wid  = threadIdx.x >> 6;
  int tile = blockIdx.x * 4 + wid;
  if (tile * 16 >= NNODES) return;
  int l15 = lane & 15, l4 = lane >> 4;

  // weight fragments from f32 arena (guarded zero-pad)
  bf16x8 w1f[KS][JT], w2f[KS][JT];
  float bv[JT];
  #pragma unroll
  for (int ks = 0; ks < KS; ++ks) {
    #pragma unroll
    for (int jt = 0; jt < JT; ++jt) {
      int col = jt * 16 + l15;
      #pragma unroll
      for (int j = 0; j < 8; ++j) {
        int k = ks * 32 + l4 * 8 + j;
        bool ok = (k < F_IN) && (col < F_OUT);
        w1f[ks][jt][j] = ok ? (short)f2b(W1[k * F_OUT + col]) : (short)0;
        w2f[ks][jt][j] = ok ? (short)f2b(W2[k * F_OUT + col]) : (short)0;
      }
    }
  }
  #pragma unroll
  for (int jt = 0; jt < JT; ++jt) {
    int col = jt * 16 + l15;
    bv[jt] = (col < F_OUT) ? Wb[col] : 0.f;
  }

  // A/B fragments: 8 consecutive f32 per lane, converted to bf16
  const float* Arow = A + (size_t)(tile * 16 + l15) * F_IN;
  bf16x8 af[KS], bfr[KS];
  #pragma unroll
  for (int ks = 0; ks < KS; ++ks) {
    #pragma unroll
    for (int j = 0; j < 8; ++j) {
      int k = ks * 32 + l4 * 8 + j;
      af[ks][j] = (k < F_IN) ? (short)f2b(Arow[k]) : (short)0;
    }
  }
  if constexpr (!DUAL) {
    const float* Brow = B + (size_t)(tile * 16 + l15) * F_IN;
    #pragma unroll
    for (int ks = 0; ks < KS; ++ks) {
      #pragma unroll
      for (int j = 0; j < 8; ++j) {
        int k = ks * 32 + l4 * 8 + j;
        bfr[ks][j] = (k < F_IN) ? (short)f2b(Brow[k]) : (short)0;
      }
    }
  }

  f32x4 acc1[JT], acc2[DUAL ? JT : 1];
  #pragma unroll
  for (int jt = 0; jt < JT; ++jt) {
    acc1[jt] = (f32x4)(0.f);
    if constexpr (DUAL) acc2[jt] = (f32x4)(0.f);
  }

  #pragma unroll
  for (int ks = 0; ks < KS; ++ks) {
    #pragma unroll
    for (int jt = 0; jt < JT; ++jt) {
      acc1[jt] = __builtin_amdgcn_mfma_f32_16x16x32_bf16(af[ks], w1f[ks][jt], acc1[jt], 0, 0, 0);
      if constexpr (DUAL)
        acc2[jt] = __builtin_amdgcn_mfma_f32_16x16x32_bf16(af[ks], w2f[ks][jt], acc2[jt], 0, 0, 0);
      else
        acc1[jt] = __builtin_amdgcn_mfma_f32_16x16x32_bf16(bfr[ks], w2f[ks][jt], acc1[jt], 0, 0, 0);
    }
  }

  #pragma unroll
  for (int jt = 0; jt < JT; ++jt) {
    int col = jt * 16 + l15;
    if (col < F_OUT) {
      #pragma unroll
      for (int r = 0; r < 4; ++r) {
        size_t o = (size_t)(tile * 16 + l4 * 4 + r) * F_OUT + col;
        if constexpr (DUAL) {
          C1[o] = acc1[jt][r];
          C2[o] = acc2[jt][r] + bv[jt];
        } else {
          float v = acc1[jt][r] + bv[jt];
          if constexpr (RELU) v = fmaxf(v, 0.f);
          C1[o] = v;
        }
      }
    }
  }
}

extern "C" void kernel_launch(void* const* d_in, const int* in_sizes, int n_in,
                              void* d_out, int out_size, void* d_ws, size_t ws_size,
                              hipStream_t stream) {
  const uint32_t* xw = (const uint32_t*)d_in[0];
  const uint32_t* ei = (const uint32_t*)d_in[1];

  char* ws = (char*)d_ws;
  size_t off = 0;
  auto carve = [&](size_t bytes) -> char* {
    char* p = ws + off;
    off = (off + bytes + 255) & ~(size_t)255;
    return p;
  };
  int* flags     = (int*)carve(8);
  int* deg       = (int*)carve((size_t)NNODES * 4);
  int* offs      = (int*)carve((size_t)(NNODES + 1) * 4);
  int* cursor    = (int*)carve((size_t)NNODES * 4);
  float* invd    = (float*)carve((size_t)NNODES * 4);
  int* csr       = (int*)carve((size_t)NEDGES * 4);
  float* xf      = (float*)carve((size_t)NNODES * 40 * 4);
  float* wf      = (float*)carve((size_t)32768 * 4);
  float* zf      = (float*)carve((size_t)NNODES * 3 * 4);
  float* b0      = (float*)carve((size_t)NNODES * 64 * 4);
  float* b1      = (float*)carve((size_t)NNODES * 64 * 4);
  float* b2      = (float*)carve((size_t)NNODES * 64 * 4);

  static const int wsz[18] = {2560, 2560, 64, 4096, 4096, 64, 192, 192, 3,
                              192, 192, 64, 4096, 4096, 64, 2560, 2560, 40};
  WPtrs wp;
  int woff = 0;
  for (int i = 0; i < 18; ++i) {
    wp.p[i] = d_in[2 + i];
    wp.sz[i] = wsz[i];
    wp.off[i] = woff;
    woff += wsz[i];
  }
  const float* W[18];
  for (int i = 0; i < 18; ++i) W[i] = wf + wp.off[i];

  // ---- detect dtypes ----
  detect_k<<<1, 64, 0, stream>>>(xw, ei, flags);

  // ---- CSR build (proven) ----
  zero_i32<<<(NNODES + 255) / 256, 256, 0, stream>>>(deg, NNODES);
  hist_k<<<(NEDGES + 255) / 256, 256, 0, stream>>>(ei, deg, flags);
  scan_k<<<1, 1024, 0, stream>>>(deg, offs, cursor, invd, NNODES);
  scatter_k<<<(NEDGES + 255) / 256, 256, 0, stream>>>(ei, cursor, csr, flags);

  // ---- convert inputs + weights to f32 scratch (proven, flag-gated) ----
  const int NX = NNODES * 40;
  cvt_in_k<false><<<(NX + 255) / 256, 256, 0, stream>>>(d_in[0], xf, NX, flags);
  cvt_in_k<true ><<<(NX + 255) / 256, 256, 0, stream>>>(d_in[0], xf, NX, flags);
  cvt_w_k<false><<<18, 256, 0, stream>>>(wp, wf, flags);
  cvt_w_k<true ><<<18, 256, 0, stream>>>(wp, wf, flags);

  const int AGG_BLOCKS = (NNODES * 64) / 256;
  const int MG = (NNODES / 16 + 3) / 4;   // 1563 blocks × 4 waves = one 16-node tile each

  // enc1 (40 -> 64)
  agg_k<40, false><<<AGG_BLOCKS, 256, 0, stream>>>(xf, csr, offs, invd, nullptr, b0);
  mgemm_k<40, 64, false, true><<<MG, 256, 0, stream>>>(b0, xf, W[0], W[1], W[2], b1, nullptr);
  // enc2 (64 -> 64)
  agg_k<64, false><<<AGG_BLOCKS, 256, 0, stream>>>(b1, csr, offs, invd, nullptr, b0);
  mgemm_k<64, 64, false, true><<<MG, 256, 0, stream>>>(b0, b1, W[3], W[4], W[5], b2, nullptr);
  // enc3 (64 -> 3): transform-first
  mgemm_k<64, 3, true, false><<<MG, 256, 0, stream>>>(b2, nullptr, W[6], W[7], W[8], b0, b1);
  agg_k<3, true><<<AGG_BLOCKS, 256, 0, stream>>>(b0, csr, offs, invd, b1, zf);
  // dec1 (3 -> 64)
  agg_k<3, false><<<AGG_BLOCKS, 256, 0, stream>>>(zf, csr, offs, invd, nullptr, b0);
  mgemm_k<3, 64, false, true><<<MG, 256, 0, stream>>>(b0, zf, W[9], W[10], W[11], b1, nullptr);
  // dec2 (64 -> 64)
  agg_k<64, false><<<AGG_BLOCKS, 256, 0, stream>>>(b1, csr, offs, invd, nullptr, b0);
  mgemm_k<64, 64, false, true><<<MG, 256, 0, stream>>>(b0, b1, W[12], W[13], W[14], b2, nullptr);
  // dec3 (64 -> 40): transform-first
  mgemm_k<64, 40, true, false><<<MG, 256, 0, stream>>>(b2, nullptr, W[15], W[16], W[17], b0, b1);
  agg_k<40, true><<<AGG_BLOCKS, 256, 0, stream>>>(b0, csr, offs, invd, b1, b2);  // x_rec f32 in b2

  // ---- write outputs in external dtype (proven, flag-gated) ----
  const int NZ = NNODES * 3;
  cvt_out_k<false><<<(NX + 255) / 256, 256, 0, stream>>>(b2, (float*)d_out, NX, flags);
  cvt_out_k<false><<<(NZ + 255) / 256, 256, 0, stream>>>(zf, (float*)d_out + NX, NZ, flags);
  cvt_out_k<true ><<<(NX + 255) / 256, 256, 0, stream>>>(b2, (ushort_t*)d_out, NX, flags);
  cvt_out_k<true ><<<(NZ + 255) / 256, 256, 0, stream>>>(zf, (ushort_t*)d_out + NX, NZ, flags);
  (void)in_sizes; (void)n_in; (void)out_size; (void)ws_size;
}

// Round 10
// 624.308 us; speedup vs baseline: 1.8908x; 1.3503x over previous
//
#include <hip/hip_runtime.h>
#include <stdint.h>

#define NNODES 100000
#define NEDGES 1600000
#define NB 98  // ceil(NNODES/1024)

typedef unsigned short ushort_t;
typedef __attribute__((ext_vector_type(8))) short bf16x8;
typedef __attribute__((ext_vector_type(4))) float f32x4;

__device__ __forceinline__ float b2f(ushort_t u) {
  union { float f; uint32_t i; } v; v.i = ((uint32_t)u) << 16; return v.f;
}
__device__ __forceinline__ float blo(uint32_t p) {
  union { float f; uint32_t i; } v; v.i = p << 16; return v.f;
}
__device__ __forceinline__ float bhi(uint32_t p) {
  union { float f; uint32_t i; } v; v.i = p & 0xffff0000u; return v.f;
}
__device__ __forceinline__ ushort_t f2b(float f) {
  union { float f; uint32_t i; } v; v.f = f;
  uint32_t r = (v.i + 0x7fffu + ((v.i >> 16) & 1u)) >> 16;
  return (ushort_t)r;
}
__device__ __forceinline__ uint32_t pack2(float lo, float hi) {
  return (uint32_t)f2b(lo) | ((uint32_t)f2b(hi) << 16);
}
__device__ __forceinline__ int clampn(int i) {
  return i < 0 ? 0 : (i >= NNODES ? NNODES - 1 : i);
}

// ---- dtype detection (proven) ----
__global__ void detect_k(const uint32_t* __restrict__ x, const uint32_t* __restrict__ ei,
                         int* __restrict__ flags) {
  if (blockIdx.x == 0 && threadIdx.x == 0) {
    int cf = 0, ci = 0;
    for (int i = 0; i < 256; ++i) {
      uint32_t u = x[i];
      uint32_t e = (u >> 7) & 0xFFu;
      if (e >= 100u && e <= 141u) cf++;
      if (ei[2 * i + 1] == 0u) ci++;
    }
    flags[0] = (cf >= 128) ? 1 : 0;
    flags[1] = (ci >= 128) ? 1 : 0;
  }
}

__global__ void zero_i32(int* __restrict__ p, int n) {
  int i = blockIdx.x * blockDim.x + threadIdx.x;
  if (i < n) p[i] = 0;
}

__global__ void hist_k(const uint32_t* __restrict__ ei, int* __restrict__ deg,
                       const int* __restrict__ flags) {
  int e = blockIdx.x * blockDim.x + threadIdx.x;
  if (e >= NEDGES) return;
  int i64 = flags[1];
  int d = i64 ? (int)ei[2 * (size_t)NEDGES + 2 * (size_t)e] : (int)ei[(size_t)NEDGES + e];
  atomicAdd(&deg[clampn(d)], 1);
}

// ---- hierarchical scan (exonerated by R4; audited) ----
__global__ __launch_bounds__(1024) void scan1_k(const int* __restrict__ deg, int* __restrict__ bsum) {
  __shared__ int wsum[16];
  int tid = threadIdx.x;
  int i = blockIdx.x * 1024 + tid;
  int v = (i < NNODES) ? deg[i] : 0;
  #pragma unroll
  for (int d = 32; d >= 1; d >>= 1) v += __shfl_down(v, d);
  if ((tid & 63) == 0) wsum[tid >> 6] = v;
  __syncthreads();
  if (tid == 0) {
    int t = 0;
    #pragma unroll
    for (int w = 0; w < 16; ++w) t += wsum[w];
    bsum[blockIdx.x] = t;
  }
}

__global__ void scan2_k(int* __restrict__ bsum, int* __restrict__ offs) {
  if (blockIdx.x == 0 && threadIdx.x == 0) {
    int run = 0;
    for (int b = 0; b < NB; ++b) { int t = bsum[b]; bsum[b] = run; run += t; }
    offs[NNODES] = run;
  }
}

__global__ __launch_bounds__(1024) void scan3_k(const int* __restrict__ deg, const int* __restrict__ bsum,
                                                int* __restrict__ offs, int* __restrict__ cursor,
                                                float* __restrict__ invd) {
  __shared__ int wsum[16];
  int tid = threadIdx.x;
  int lane = tid & 63, wid = tid >> 6;
  int i = blockIdx.x * 1024 + tid;
  int v = (i < NNODES) ? deg[i] : 0;
  int s = v;
  #pragma unroll
  for (int d = 1; d < 64; d <<= 1) {
    int t = __shfl_up(s, d);
    if (lane >= d) s += t;
  }
  if (lane == 63) wsum[wid] = s;
  __syncthreads();
  int wprefix = 0;
  #pragma unroll
  for (int w = 0; w < 16; ++w)
    if (w < wid) wprefix += wsum[w];
  if (i < NNODES) {
    int excl = bsum[blockIdx.x] + wprefix + s - v;
    offs[i] = excl;
    cursor[i] = excl;
    invd[i] = 1.0f / fmaxf((float)v, 1.0f);
  }
}

__global__ void scatter_k(const uint32_t* __restrict__ ei, int* __restrict__ cursor,
                          int* __restrict__ csr, const int* __restrict__ flags) {
  int e = blockIdx.x * blockDim.x + threadIdx.x;
  if (e >= NEDGES) return;
  int i64 = flags[1];
  int s, d;
  if (i64) {
    s = (int)ei[2 * (size_t)e];
    d = (int)ei[2 * (size_t)NEDGES + 2 * (size_t)e];
  } else {
    s = (int)ei[e];
    d = (int)ei[(size_t)NEDGES + e];
  }
  int p = atomicAdd(&cursor[clampn(d)], 1);
  if (p >= 0 && p < NEDGES) csr[p] = clampn(s);
}

// ---- cvt kernels (cvt-style; only place ushort input reads happen) ----
template <bool BF16>
__global__ void cvt_packx_k(const void* __restrict__ src, uint32_t* __restrict__ dst, int npairs,
                            const int* __restrict__ flags) {
  if (flags[0] != (BF16 ? 1 : 0)) return;
  int i = blockIdx.x * blockDim.x + threadIdx.x;
  if (i < npairs) {
    if constexpr (BF16) dst[i] = ((const uint32_t*)src)[i];       // bf16 input is already pair-packed
    else {
      const float* s = (const float*)src;
      dst[i] = pack2(s[2 * i], s[2 * i + 1]);
    }
  }
}

template <bool BF16>
__global__ void cvt_outp_k(const uint32_t* __restrict__ src, void* __restrict__ dst, int npairs,
                           const int* __restrict__ flags) {
  if (flags[0] != (BF16 ? 1 : 0)) return;
  int i = blockIdx.x * blockDim.x + threadIdx.x;
  if (i < npairs) {
    if constexpr (BF16) ((uint32_t*)dst)[i] = src[i];
    else {
      uint32_t w = src[i];
      float* d = (float*)dst;
      d[2 * i] = blo(w);
      d[2 * i + 1] = bhi(w);
    }
  }
}

template <bool BF16>
__global__ void cvt_out_k(const float* __restrict__ src, void* __restrict__ dst, int n,
                          const int* __restrict__ flags) {
  if (flags[0] != (BF16 ? 1 : 0)) return;
  int i = blockIdx.x * blockDim.x + threadIdx.x;
  if (i < n) {
    if constexpr (BF16) ((ushort_t*)dst)[i] = f2b(src[i]);
    else ((float*)dst)[i] = src[i];
  }
}

struct WPtrs { const void* p[18]; int sz[18]; int off[18]; };

template <bool BF16>
__global__ void cvt_w_k(WPtrs w, float* __restrict__ dst, const int* __restrict__ flags) {
  if (flags[0] != (BF16 ? 1 : 0)) return;
  int a = blockIdx.x;
  int sz = w.sz[a], off = w.off[a];
  for (int t = threadIdx.x; t < sz; t += blockDim.x) {
    dst[off + t] = BF16 ? b2f(((const ushort_t*)w.p[a])[t]) : ((const float*)w.p[a])[t];
  }
}

// ---- f32 aggregation (proven; z path only) ----
template <int F, bool ADD_U>
__global__ __launch_bounds__(256) void agg_k(const float* __restrict__ feat, const int* __restrict__ csr,
                                             const int* __restrict__ offs, const float* __restrict__ invdeg,
                                             const float* __restrict__ u, float* __restrict__ out) {
  int lane = threadIdx.x & 63;
  int n = (blockIdx.x * blockDim.x + threadIdx.x) >> 6;
  if (n >= NNODES) return;
  int k0 = offs[n], k1 = offs[n + 1];
  float acc = 0.f;
  int k = k0;
  for (; k + 4 <= k1; k += 4) {
    int n0 = csr[k], n1 = csr[k + 1], n2 = csr[k + 2], n3 = csr[k + 3];
    if (lane < F) {
      acc += feat[(size_t)n0 * F + lane];
      acc += feat[(size_t)n1 * F + lane];
      acc += feat[(size_t)n2 * F + lane];
      acc += feat[(size_t)n3 * F + lane];
    }
  }
  for (; k < k1; ++k) {
    int nn = csr[k];
    if (lane < F) acc += feat[(size_t)nn * F + lane];
  }
  if (lane < F) {
    float val = acc * invdeg[n];
    if constexpr (ADD_U) val += u[(size_t)n * F + lane];
    out[(size_t)n * F + lane] = val;
  }
}

// ---- packed-bf16 aggregation: 2 nodes per wave; lane pair p handles features (2p, 2p+1) ----
template <int PAIRS, bool ADD_U>
__global__ __launch_bounds__(256) void aggp_k(const uint32_t* __restrict__ feat, const int* __restrict__ csr,
                                              const int* __restrict__ offs, const float* __restrict__ invd,
                                              const uint32_t* __restrict__ u, uint32_t* __restrict__ out) {
  int lane = threadIdx.x & 63;
  int wave = (blockIdx.x * blockDim.x + threadIdx.x) >> 6;
  int half = lane >> 5;
  int p = lane & 31;
  int n = wave * 2 + half;
  if (n >= NNODES) return;
  int k0 = offs[n], k1 = offs[n + 1];
  float aL = 0.f, aH = 0.f;
  int k = k0;
  for (; k + 4 <= k1; k += 4) {
    int n0 = csr[k], n1 = csr[k + 1], n2 = csr[k + 2], n3 = csr[k + 3];
    if (p < PAIRS) {
      uint32_t w0 = feat[(size_t)n0 * PAIRS + p];
      uint32_t w1 = feat[(size_t)n1 * PAIRS + p];
      uint32_t w2 = feat[(size_t)n2 * PAIRS + p];
      uint32_t w3 = feat[(size_t)n3 * PAIRS + p];
      aL += blo(w0) + blo(w1) + blo(w2) + blo(w3);
      aH += bhi(w0) + bhi(w1) + bhi(w2) + bhi(w3);
    }
  }
  for (; k < k1; ++k) {
    int nn = csr[k];
    if (p < PAIRS) {
      uint32_t w = feat[(size_t)nn * PAIRS + p];
      aL += blo(w);
      aH += bhi(w);
    }
  }
  if (p < PAIRS) {
    float iv = invd[n];
    float vL = aL * iv, vH = aH * iv;
    if constexpr (ADD_U) {
      uint32_t uw = u[(size_t)n * PAIRS + p];
      vL += blo(uw);
      vH += bhi(uw);
    }
    out[(size_t)n * PAIRS + p] = pack2(vL, vH);
  }
}

// ---- MFMA fused linear; PIN: A/B are packed-bf16 uint32 tables; POUT: packed output ----
// DUAL=false: C1 = act(A@W1 + B@W2 + bias) ; DUAL=true: C1 = A@W1 ; C2 = A@W2 + bias
// Weights always from f32 arena (f2b in-register; proven R9 path).
template <int F_IN, int F_OUT, bool DUAL, bool RELU, bool PIN, bool POUT>
__global__ __launch_bounds__(256) void mgemm_k(const void* __restrict__ Av, const void* __restrict__ Bv,
                                               const float* __restrict__ W1, const float* __restrict__ W2,
                                               const float* __restrict__ Wb,
                                               void* __restrict__ C1v, void* __restrict__ C2v) {
  constexpr int KS = (F_IN + 31) / 32;
  constexpr int JT = (F_OUT + 15) / 16;
  constexpr int PP = F_IN / 2;   // pairs per row when PIN (even F_IN only)
  int lane = threadIdx.x & 63;
  int wid  = threadIdx.x >> 6;
  int tile = blockIdx.x * 4 + wid;
  if (tile * 16 >= NNODES) return;
  int l15 = lane & 15, l4 = lane >> 4;

  bf16x8 w1f[KS][JT], w2f[KS][JT];
  float bv[JT];
  #pragma unroll
  for (int ks = 0; ks < KS; ++ks) {
    #pragma unroll
    for (int jt = 0; jt < JT; ++jt) {
      int col = jt * 16 + l15;
      #pragma unroll
      for (int j = 0; j < 8; ++j) {
        int k = ks * 32 + l4 * 8 + j;
        bool ok = (k < F_IN) && (col < F_OUT);
        w1f[ks][jt][j] = ok ? (short)f2b(W1[k * F_OUT + col]) : (short)0;
        w2f[ks][jt][j] = ok ? (short)f2b(W2[k * F_OUT + col]) : (short)0;
      }
    }
  }
  #pragma unroll
  for (int jt = 0; jt < JT; ++jt) {
    int col = jt * 16 + l15;
    bv[jt] = (col < F_OUT) ? Wb[col] : 0.f;
  }

  int row = tile * 16 + l15;
  bf16x8 af[KS], bfr[KS];
  if constexpr (PIN) {
    const uint32_t* Arow = (const uint32_t*)Av + (size_t)row * PP;
    #pragma unroll
    for (int ks = 0; ks < KS; ++ks) {
      #pragma unroll
      for (int w4 = 0; w4 < 4; ++w4) {
        int word = ks * 16 + l4 * 4 + w4;
        uint32_t v = (word < PP) ? Arow[word] : 0u;
        af[ks][2 * w4]     = (short)(v & 0xffffu);
        af[ks][2 * w4 + 1] = (short)(v >> 16);
      }
    }
    if constexpr (!DUAL) {
      const uint32_t* Brow = (const uint32_t*)Bv + (size_t)row * PP;
      #pragma unroll
      for (int ks = 0; ks < KS; ++ks) {
        #pragma unroll
        for (int w4 = 0; w4 < 4; ++w4) {
          int word = ks * 16 + l4 * 4 + w4;
          uint32_t v = (word < PP) ? Brow[word] : 0u;
          bfr[ks][2 * w4]     = (short)(v & 0xffffu);
          bfr[ks][2 * w4 + 1] = (short)(v >> 16);
        }
      }
    }
  } else {
    const float* Arow = (const float*)Av + (size_t)row * F_IN;
    #pragma unroll
    for (int ks = 0; ks < KS; ++ks) {
      #pragma unroll
      for (int j = 0; j < 8; ++j) {
        int k = ks * 32 + l4 * 8 + j;
        af[ks][j] = (k < F_IN) ? (short)f2b(Arow[k]) : (short)0;
      }
    }
    if constexpr (!DUAL) {
      const float* Brow = (const float*)Bv + (size_t)row * F_IN;
      #pragma unroll
      for (int ks = 0; ks < KS; ++ks) {
        #pragma unroll
        for (int j = 0; j < 8; ++j) {
          int k = ks * 32 + l4 * 8 + j;
          bfr[ks][j] = (k < F_IN) ? (short)f2b(Brow[k]) : (short)0;
        }
      }
    }
  }

  f32x4 acc1[JT], acc2[DUAL ? JT : 1];
  #pragma unroll
  for (int jt = 0; jt < JT; ++jt) {
    acc1[jt] = (f32x4)(0.f);
    if constexpr (DUAL) acc2[jt] = (f32x4)(0.f);
  }

  #pragma unroll
  for (int ks = 0; ks < KS; ++ks) {
    #pragma unroll
    for (int jt = 0; jt < JT; ++jt) {
      acc1[jt] = __builtin_amdgcn_mfma_f32_16x16x32_bf16(af[ks], w1f[ks][jt], acc1[jt], 0, 0, 0);
      if constexpr (DUAL)
        acc2[jt] = __builtin_amdgcn_mfma_f32_16x16x32_bf16(af[ks], w2f[ks][jt], acc2[jt], 0, 0, 0);
      else
        acc1[jt] = __builtin_amdgcn_mfma_f32_16x16x32_bf16(bfr[ks], w2f[ks][jt], acc1[jt], 0, 0, 0);
    }
  }

  // epilogue: D col=lane&15, row=(lane>>4)*4+reg (m89-verified)
  #pragma unroll
  for (int jt = 0; jt < JT; ++jt) {
    int col = jt * 16 + l15;
    #pragma unroll
    for (int r = 0; r < 4; ++r) {
      int orow = tile * 16 + l4 * 4 + r;
      if constexpr (DUAL) {
        float v1 = acc1[jt][r];
        float v2 = acc2[jt][r] + bv[jt];
        if constexpr (POUT) {
          float p1 = __shfl_xor(v1, 1);
          float p2 = __shfl_xor(v2, 1);
          if (((lane & 1) == 0) && col < F_OUT) {
            ((uint32_t*)C1v)[(size_t)orow * (F_OUT / 2) + (col >> 1)] = pack2(v1, p1);
            ((uint32_t*)C2v)[(size_t)orow * (F_OUT / 2) + (col >> 1)] = pack2(v2, p2);
          }
        } else {
          if (col < F_OUT) {
            ((float*)C1v)[(size_t)orow * F_OUT + col] = v1;
            ((float*)C2v)[(size_t)orow * F_OUT + col] = v2;
          }
        }
      } else {
        float v = acc1[jt][r] + bv[jt];
        if constexpr (RELU) v = fmaxf(v, 0.f);
        if constexpr (POUT) {
          float pv = __shfl_xor(v, 1);
          if (((lane & 1) == 0) && col < F_OUT)
            ((uint32_t*)C1v)[(size_t)orow * (F_OUT / 2) + (col >> 1)] = pack2(v, pv);
        } else {
          if (col < F_OUT)
            ((float*)C1v)[(size_t)orow * F_OUT + col] = v;
        }
      }
    }
  }
}

extern "C" void kernel_launch(void* const* d_in, const int* in_sizes, int n_in,
                              void* d_out, int out_size, void* d_ws, size_t ws_size,
                              hipStream_t stream) {
  const uint32_t* xw = (const uint32_t*)d_in[0];
  const uint32_t* ei = (const uint32_t*)d_in[1];

  char* ws = (char*)d_ws;
  size_t off = 0;
  auto carve = [&](size_t bytes) -> char* {
    char* p = ws + off;
    off = (off + bytes + 255) & ~(size_t)255;
    return p;
  };
  int* flags     = (int*)carve(8);
  int* deg       = (int*)carve((size_t)NNODES * 4);
  int* offs      = (int*)carve((size_t)(NNODES + 1) * 4);
  int* cursor    = (int*)carve((size_t)NNODES * 4);
  float* invd    = (float*)carve((size_t)NNODES * 4);
  int* bsum      = (int*)carve((size_t)NB * 4);
  int* csr       = (int*)carve((size_t)NEDGES * 4);
  float* wf      = (float*)carve((size_t)32768 * 4);
  uint32_t* xp   = (uint32_t*)carve((size_t)NNODES * 20 * 4);
  uint32_t* mp   = (uint32_t*)carve((size_t)NNODES * 20 * 4);
  uint32_t* b0p  = (uint32_t*)carve((size_t)NNODES * 32 * 4);
  uint32_t* b1p  = (uint32_t*)carve((size_t)NNODES * 32 * 4);
  uint32_t* b2p  = (uint32_t*)carve((size_t)NNODES * 32 * 4);
  uint32_t* y40p = (uint32_t*)carve((size_t)NNODES * 20 * 4);
  uint32_t* u40p = (uint32_t*)carve((size_t)NNODES * 20 * 4);
  uint32_t* xrp  = (uint32_t*)carve((size_t)NNODES * 20 * 4);
  float* y3f     = (float*)carve((size_t)NNODES * 3 * 4);
  float* u3f     = (float*)carve((size_t)NNODES * 3 * 4);
  float* zf      = (float*)carve((size_t)NNODES * 3 * 4);
  float* m3f     = (float*)carve((size_t)NNODES * 3 * 4);

  static const int wsz[18] = {2560, 2560, 64, 4096, 4096, 64, 192, 192, 3,
                              192, 192, 64, 4096, 4096, 64, 2560, 2560, 40};
  WPtrs wp;
  int woff = 0;
  for (int i = 0; i < 18; ++i) {
    wp.p[i] = d_in[2 + i];
    wp.sz[i] = wsz[i];
    wp.off[i] = woff;
    woff += wsz[i];
  }
  const float* W[18];
  for (int i = 0; i < 18; ++i) W[i] = wf + wp.off[i];

  // ---- detect + CSR build ----
  detect_k<<<1, 64, 0, stream>>>(xw, ei, flags);
  zero_i32<<<(NNODES + 255) / 256, 256, 0, stream>>>(deg, NNODES);
  hist_k<<<(NEDGES + 255) / 256, 256, 0, stream>>>(ei, deg, flags);
  scan1_k<<<NB, 1024, 0, stream>>>(deg, bsum);
  scan2_k<<<1, 64, 0, stream>>>(bsum, offs);
  scan3_k<<<NB, 1024, 0, stream>>>(deg, bsum, offs, cursor, invd);
  scatter_k<<<(NEDGES + 255) / 256, 256, 0, stream>>>(ei, cursor, csr, flags);

  // ---- convert x (packed) + weights (f32 arena), flag-gated ----
  const int NXP = NNODES * 20;   // x pairs
  cvt_packx_k<false><<<(NXP + 255) / 256, 256, 0, stream>>>(d_in[0], xp, NXP, flags);
  cvt_packx_k<true ><<<(NXP + 255) / 256, 256, 0, stream>>>(d_in[0], xp, NXP, flags);
  cvt_w_k<false><<<18, 256, 0, stream>>>(wp, wf, flags);
  cvt_w_k<true ><<<18, 256, 0, stream>>>(wp, wf, flags);

  const int AGG_BLOCKS  = (NNODES * 64) / 256;        // f32 agg: 1 node/wave
  const int AGGP_BLOCKS = (NNODES / 2 * 64) / 256;    // packed agg: 2 nodes/wave
  const int MG = (NNODES / 16 + 3) / 4;

  // enc1 (40 -> 64)
  aggp_k<20, false><<<AGGP_BLOCKS, 256, 0, stream>>>(xp, csr, offs, invd, nullptr, mp);
  mgemm_k<40, 64, false, true, true, true><<<MG, 256, 0, stream>>>(mp, xp, W[0], W[1], W[2], b1p, nullptr);
  // enc2 (64 -> 64)
  aggp_k<32, false><<<AGGP_BLOCKS, 256, 0, stream>>>(b1p, csr, offs, invd, nullptr, b0p);
  mgemm_k<64, 64, false, true, true, true><<<MG, 256, 0, stream>>>(b0p, b1p, W[3], W[4], W[5], b2p, nullptr);
  // enc3 (64 -> 3): transform-first; z path f32
  mgemm_k<64, 3, true, false, true, false><<<MG, 256, 0, stream>>>(b2p, nullptr, W[6], W[7], W[8], y3f, u3f);
  agg_k<3, true><<<AGG_BLOCKS, 256, 0, stream>>>(y3f, csr, offs, invd, u3f, zf);
  // dec1 (3 -> 64)
  agg_k<3, false><<<AGG_BLOCKS, 256, 0, stream>>>(zf, csr, offs, invd, nullptr, m3f);
  mgemm_k<3, 64, false, true, false, true><<<MG, 256, 0, stream>>>(m3f, zf, W[9], W[10], W[11], b1p, nullptr);
  // dec2 (64 -> 64)
  aggp_k<32, false><<<AGGP_BLOCKS, 256, 0, stream>>>(b1p, csr, offs, invd, nullptr, b0p);
  mgemm_k<64, 64, false, true, true, true><<<MG, 256, 0, stream>>>(b0p, b1p, W[12], W[13], W[14], b2p, nullptr);
  // dec3 (64 -> 40): transform-first
  mgemm_k<64, 40, true, false, true, true><<<MG, 256, 0, stream>>>(b2p, nullptr, W[15], W[16], W[17], y40p, u40p);
  aggp_k<20, true><<<AGGP_BLOCKS, 256, 0, stream>>>(y40p, csr, offs, invd, u40p, xrp);

  // ---- outputs ----
  const int NX = NNODES * 40;
  const int NZ = NNODES * 3;
  cvt_outp_k<false><<<(NXP + 255) / 256, 256, 0, stream>>>(xrp, d_out, NXP, flags);
  cvt_outp_k<true ><<<(NXP + 255) / 256, 256, 0, stream>>>(xrp, d_out, NXP, flags);
  cvt_out_k<false><<<(NZ + 255) / 256, 256, 0, stream>>>(zf, (float*)d_out + NX, NZ, flags);
  cvt_out_k<true ><<<(NZ + 255) / 256, 256, 0, stream>>>(zf, (ushort_t*)d_out + NX, NZ, flags);
  (void)in_sizes; (void)n_in; (void)out_size; (void)ws_size;
}

// Round 11
// 572.934 us; speedup vs baseline: 2.0603x; 1.0897x over previous
//
#include <hip/hip_runtime.h>
#include <stdint.h>

#define NNODES 100000
#define NEDGES 1600000
#define NB 98  // ceil(NNODES/1024)

typedef unsigned short ushort_t;
typedef __attribute__((ext_vector_type(8))) short bf16x8;
typedef __attribute__((ext_vector_type(4))) float f32x4;

__device__ __forceinline__ float b2f(ushort_t u) {
  union { float f; uint32_t i; } v; v.i = ((uint32_t)u) << 16; return v.f;
}
__device__ __forceinline__ float blo(uint32_t p) {
  union { float f; uint32_t i; } v; v.i = p << 16; return v.f;
}
__device__ __forceinline__ float bhi(uint32_t p) {
  union { float f; uint32_t i; } v; v.i = p & 0xffff0000u; return v.f;
}
__device__ __forceinline__ ushort_t f2b(float f) {
  union { float f; uint32_t i; } v; v.f = f;
  uint32_t r = (v.i + 0x7fffu + ((v.i >> 16) & 1u)) >> 16;
  return (ushort_t)r;
}
__device__ __forceinline__ uint32_t pack2(float lo, float hi) {
  return (uint32_t)f2b(lo) | ((uint32_t)f2b(hi) << 16);
}
__device__ __forceinline__ int clampn(int i) {
  return i < 0 ? 0 : (i >= NNODES ? NNODES - 1 : i);
}

// ---- dtype detection (proven) ----
__global__ void detect_k(const uint32_t* __restrict__ x, const uint32_t* __restrict__ ei,
                         int* __restrict__ flags) {
  if (blockIdx.x == 0 && threadIdx.x == 0) {
    int cf = 0, ci = 0;
    for (int i = 0; i < 256; ++i) {
      uint32_t u = x[i];
      uint32_t e = (u >> 7) & 0xFFu;
      if (e >= 100u && e <= 141u) cf++;
      if (ei[2 * i + 1] == 0u) ci++;
    }
    flags[0] = (cf >= 128) ? 1 : 0;
    flags[1] = (ci >= 128) ? 1 : 0;
  }
}

__global__ void zero_i32(int* __restrict__ p, int n) {
  int i = blockIdx.x * blockDim.x + threadIdx.x;
  if (i < n) p[i] = 0;
}

__global__ void hist_k(const uint32_t* __restrict__ ei, int* __restrict__ deg,
                       const int* __restrict__ flags) {
  int e = blockIdx.x * blockDim.x + threadIdx.x;
  if (e >= NEDGES) return;
  int i64 = flags[1];
  int d = i64 ? (int)ei[2 * (size_t)NEDGES + 2 * (size_t)e] : (int)ei[(size_t)NEDGES + e];
  atomicAdd(&deg[clampn(d)], 1);
}

// ---- hierarchical scan (proven R10) ----
__global__ __launch_bounds__(1024) void scan1_k(const int* __restrict__ deg, int* __restrict__ bsum) {
  __shared__ int wsum[16];
  int tid = threadIdx.x;
  int i = blockIdx.x * 1024 + tid;
  int v = (i < NNODES) ? deg[i] : 0;
  #pragma unroll
  for (int d = 32; d >= 1; d >>= 1) v += __shfl_down(v, d);
  if ((tid & 63) == 0) wsum[tid >> 6] = v;
  __syncthreads();
  if (tid == 0) {
    int t = 0;
    #pragma unroll
    for (int w = 0; w < 16; ++w) t += wsum[w];
    bsum[blockIdx.x] = t;
  }
}

__global__ void scan2_k(int* __restrict__ bsum, int* __restrict__ offs) {
  if (blockIdx.x == 0 && threadIdx.x == 0) {
    int run = 0;
    for (int b = 0; b < NB; ++b) { int t = bsum[b]; bsum[b] = run; run += t; }
    offs[NNODES] = run;
  }
}

__global__ __launch_bounds__(1024) void scan3_k(const int* __restrict__ deg, const int* __restrict__ bsum,
                                                int* __restrict__ offs, int* __restrict__ cursor,
                                                float* __restrict__ invd) {
  __shared__ int wsum[16];
  int tid = threadIdx.x;
  int lane = tid & 63, wid = tid >> 6;
  int i = blockIdx.x * 1024 + tid;
  int v = (i < NNODES) ? deg[i] : 0;
  int s = v;
  #pragma unroll
  for (int d = 1; d < 64; d <<= 1) {
    int t = __shfl_up(s, d);
    if (lane >= d) s += t;
  }
  if (lane == 63) wsum[wid] = s;
  __syncthreads();
  int wprefix = 0;
  #pragma unroll
  for (int w = 0; w < 16; ++w)
    if (w < wid) wprefix += wsum[w];
  if (i < NNODES) {
    int excl = bsum[blockIdx.x] + wprefix + s - v;
    offs[i] = excl;
    cursor[i] = excl;
    invd[i] = 1.0f / fmaxf((float)v, 1.0f);
  }
}

// ---- 4-pass windowed scatter: csr write window [offs[lo], offs[hi]) ~1.6MB stays L2-hot ----
__global__ void scatter4_k(const uint32_t* __restrict__ ei, int* __restrict__ cursor,
                           int* __restrict__ csr, const int* __restrict__ flags,
                           int lo, int hi) {
  int e = blockIdx.x * blockDim.x + threadIdx.x;
  if (e >= NEDGES) return;
  int i64 = flags[1];
  int s, d;
  if (i64) {
    d = (int)ei[2 * (size_t)NEDGES + 2 * (size_t)e];
    d = clampn(d);
    if (d < lo || d >= hi) return;
    s = (int)ei[2 * (size_t)e];
  } else {
    d = (int)ei[(size_t)NEDGES + e];
    d = clampn(d);
    if (d < lo || d >= hi) return;
    s = (int)ei[e];
  }
  int p = atomicAdd(&cursor[d], 1);
  if (p >= 0 && p < NEDGES) csr[p] = clampn(s);
}

// ---- cvt kernels (cvt-style; only place ushort input reads happen) ----
template <bool BF16>
__global__ void cvt_packx_k(const void* __restrict__ src, uint32_t* __restrict__ dst, int npairs,
                            const int* __restrict__ flags) {
  if (flags[0] != (BF16 ? 1 : 0)) return;
  int i = blockIdx.x * blockDim.x + threadIdx.x;
  if (i < npairs) {
    if constexpr (BF16) dst[i] = ((const uint32_t*)src)[i];
    else {
      const float* s = (const float*)src;
      dst[i] = pack2(s[2 * i], s[2 * i + 1]);
    }
  }
}

template <bool BF16>
__global__ void cvt_outp_k(const uint32_t* __restrict__ src, void* __restrict__ dst, int npairs,
                           const int* __restrict__ flags) {
  if (flags[0] != (BF16 ? 1 : 0)) return;
  int i = blockIdx.x * blockDim.x + threadIdx.x;
  if (i < npairs) {
    if constexpr (BF16) ((uint32_t*)dst)[i] = src[i];
    else {
      uint32_t w = src[i];
      float* d = (float*)dst;
      d[2 * i] = blo(w);
      d[2 * i + 1] = bhi(w);
    }
  }
}

template <bool BF16>
__global__ void cvt_out_k(const float* __restrict__ src, void* __restrict__ dst, int n,
                          const int* __restrict__ flags) {
  if (flags[0] != (BF16 ? 1 : 0)) return;
  int i = blockIdx.x * blockDim.x + threadIdx.x;
  if (i < n) {
    if constexpr (BF16) ((ushort_t*)dst)[i] = f2b(src[i]);
    else ((float*)dst)[i] = src[i];
  }
}

struct WPtrs { const void* p[18]; int sz[18]; int off[18]; };

template <bool BF16>
__global__ void cvt_w_k(WPtrs w, float* __restrict__ dst, const int* __restrict__ flags) {
  if (flags[0] != (BF16 ? 1 : 0)) return;
  int a = blockIdx.x;
  int sz = w.sz[a], off = w.off[a];
  for (int t = threadIdx.x; t < sz; t += blockDim.x) {
    dst[off + t] = BF16 ? b2f(((const ushort_t*)w.p[a])[t]) : ((const float*)w.p[a])[t];
  }
}

// ---- F=3 aggregation: one LANE per node (64x lane density vs wave-per-node) ----
template <bool ADD_U>
__global__ __launch_bounds__(256) void agg3_k(const float* __restrict__ feat, const int* __restrict__ csr,
                                              const int* __restrict__ offs, const float* __restrict__ invd,
                                              const float* __restrict__ u, float* __restrict__ out) {
  int n = blockIdx.x * blockDim.x + threadIdx.x;
  if (n >= NNODES) return;
  int k0 = offs[n], k1 = offs[n + 1];
  float a0 = 0.f, a1 = 0.f, a2 = 0.f;
  int k = k0;
  for (; k + 4 <= k1; k += 4) {
    const float* r0 = feat + (size_t)csr[k] * 3;
    const float* r1 = feat + (size_t)csr[k + 1] * 3;
    const float* r2 = feat + (size_t)csr[k + 2] * 3;
    const float* r3 = feat + (size_t)csr[k + 3] * 3;
    a0 += r0[0] + r1[0] + r2[0] + r3[0];
    a1 += r0[1] + r1[1] + r2[1] + r3[1];
    a2 += r0[2] + r1[2] + r2[2] + r3[2];
  }
  for (; k < k1; ++k) {
    const float* r = feat + (size_t)csr[k] * 3;
    a0 += r[0]; a1 += r[1]; a2 += r[2];
  }
  float iv = invd[n];
  a0 *= iv; a1 *= iv; a2 *= iv;
  if constexpr (ADD_U) {
    a0 += u[(size_t)n * 3];
    a1 += u[(size_t)n * 3 + 1];
    a2 += u[(size_t)n * 3 + 2];
  }
  out[(size_t)n * 3]     = a0;
  out[(size_t)n * 3 + 1] = a1;
  out[(size_t)n * 3 + 2] = a2;
}

// ---- packed-bf16 aggregation v2: ONE node per wave; 2 neighbors x 32 lane-pairs; unroll 4 ----
template <int PAIRS, bool ADD_U>
__global__ __launch_bounds__(256) void aggp2_k(const uint32_t* __restrict__ feat, const int* __restrict__ csr,
                                               const int* __restrict__ offs, const float* __restrict__ invd,
                                               const uint32_t* __restrict__ u, uint32_t* __restrict__ out) {
  int lane = threadIdx.x & 63;
  int n = (blockIdx.x * blockDim.x + threadIdx.x) >> 6;
  if (n >= NNODES) return;
  int half = lane >> 5;
  int p = lane & 31;
  int k0 = offs[n], k1 = offs[n + 1];
  float aL = 0.f, aH = 0.f;
  int k = k0;
  for (; k + 8 <= k1; k += 8) {
    int i0 = csr[k + half], i1 = csr[k + 2 + half], i2 = csr[k + 4 + half], i3 = csr[k + 6 + half];
    if (p < PAIRS) {
      uint32_t w0 = feat[(size_t)i0 * PAIRS + p];
      uint32_t w1 = feat[(size_t)i1 * PAIRS + p];
      uint32_t w2 = feat[(size_t)i2 * PAIRS + p];
      uint32_t w3 = feat[(size_t)i3 * PAIRS + p];
      aL += blo(w0) + blo(w1) + blo(w2) + blo(w3);
      aH += bhi(w0) + bhi(w1) + bhi(w2) + bhi(w3);
    }
  }
  for (; k < k1; k += 2) {
    int kk = k + half;
    if (kk < k1 && p < PAIRS) {
      uint32_t w = feat[(size_t)csr[kk] * PAIRS + p];
      aL += blo(w);
      aH += bhi(w);
    }
  }
  aL += __shfl_xor(aL, 32);
  aH += __shfl_xor(aH, 32);
  if (half == 0 && p < PAIRS) {
    float iv = invd[n];
    float vL = aL * iv, vH = aH * iv;
    if constexpr (ADD_U) {
      uint32_t uw = u[(size_t)n * PAIRS + p];
      vL += blo(uw);
      vH += bhi(uw);
    }
    out[(size_t)n * PAIRS + p] = pack2(vL, vH);
  }
}

// ---- MFMA fused linear (byte-identical to R10) ----
template <int F_IN, int F_OUT, bool DUAL, bool RELU, bool PIN, bool POUT>
__global__ __launch_bounds__(256) void mgemm_k(const void* __restrict__ Av, const void* __restrict__ Bv,
                                               const float* __restrict__ W1, const float* __restrict__ W2,
                                               const float* __restrict__ Wb,
                                               void* __restrict__ C1v, void* __restrict__ C2v) {
  constexpr int KS = (F_IN + 31) / 32;
  constexpr int JT = (F_OUT + 15) / 16;
  constexpr int PP = F_IN / 2;
  int lane = threadIdx.x & 63;
  int wid  = threadIdx.x >> 6;
  int tile = blockIdx.x * 4 + wid;
  if (tile * 16 >= NNODES) return;
  int l15 = lane & 15, l4 = lane >> 4;

  bf16x8 w1f[KS][JT], w2f[KS][JT];
  float bv[JT];
  #pragma unroll
  for (int ks = 0; ks < KS; ++ks) {
    #pragma unroll
    for (int jt = 0; jt < JT; ++jt) {
      int col = jt * 16 + l15;
      #pragma unroll
      for (int j = 0; j < 8; ++j) {
        int k = ks * 32 + l4 * 8 + j;
        bool ok = (k < F_IN) && (col < F_OUT);
        w1f[ks][jt][j] = ok ? (short)f2b(W1[k * F_OUT + col]) : (short)0;
        w2f[ks][jt][j] = ok ? (short)f2b(W2[k * F_OUT + col]) : (short)0;
      }
    }
  }
  #pragma unroll
  for (int jt = 0; jt < JT; ++jt) {
    int col = jt * 16 + l15;
    bv[jt] = (col < F_OUT) ? Wb[col] : 0.f;
  }

  int row = tile * 16 + l15;
  bf16x8 af[KS], bfr[KS];
  if constexpr (PIN) {
    const uint32_t* Arow = (const uint32_t*)Av + (size_t)row * PP;
    #pragma unroll
    for (int ks = 0; ks < KS; ++ks) {
      #pragma unroll
      for (int w4 = 0; w4 < 4; ++w4) {
        int word = ks * 16 + l4 * 4 + w4;
        uint32_t v = (word < PP) ? Arow[word] : 0u;
        af[ks][2 * w4]     = (short)(v & 0xffffu);
        af[ks][2 * w4 + 1] = (short)(v >> 16);
      }
    }
    if constexpr (!DUAL) {
      const uint32_t* Brow = (const uint32_t*)Bv + (size_t)row * PP;
      #pragma unroll
      for (int ks = 0; ks < KS; ++ks) {
        #pragma unroll
        for (int w4 = 0; w4 < 4; ++w4) {
          int word = ks * 16 + l4 * 4 + w4;
          uint32_t v = (word < PP) ? Brow[word] : 0u;
          bfr[ks][2 * w4]     = (short)(v & 0xffffu);
          bfr[ks][2 * w4 + 1] = (short)(v >> 16);
        }
      }
    }
  } else {
    const float* Arow = (const float*)Av + (size_t)row * F_IN;
    #pragma unroll
    for (int ks = 0; ks < KS; ++ks) {
      #pragma unroll
      for (int j = 0; j < 8; ++j) {
        int k = ks * 32 + l4 * 8 + j;
        af[ks][j] = (k < F_IN) ? (short)f2b(Arow[k]) : (short)0;
      }
    }
    if constexpr (!DUAL) {
      const float* Brow = (const float*)Bv + (size_t)row * F_IN;
      #pragma unroll
      for (int ks = 0; ks < KS; ++ks) {
        #pragma unroll
        for (int j = 0; j < 8; ++j) {
          int k = ks * 32 + l4 * 8 + j;
          bfr[ks][j] = (k < F_IN) ? (short)f2b(Brow[k]) : (short)0;
        }
      }
    }
  }

  f32x4 acc1[JT], acc2[DUAL ? JT : 1];
  #pragma unroll
  for (int jt = 0; jt < JT; ++jt) {
    acc1[jt] = (f32x4)(0.f);
    if constexpr (DUAL) acc2[jt] = (f32x4)(0.f);
  }

  #pragma unroll
  for (int ks = 0; ks < KS; ++ks) {
    #pragma unroll
    for (int jt = 0; jt < JT; ++jt) {
      acc1[jt] = __builtin_amdgcn_mfma_f32_16x16x32_bf16(af[ks], w1f[ks][jt], acc1[jt], 0, 0, 0);
      if constexpr (DUAL)
        acc2[jt] = __builtin_amdgcn_mfma_f32_16x16x32_bf16(af[ks], w2f[ks][jt], acc2[jt], 0, 0, 0);
      else
        acc1[jt] = __builtin_amdgcn_mfma_f32_16x16x32_bf16(bfr[ks], w2f[ks][jt], acc1[jt], 0, 0, 0);
    }
  }

  #pragma unroll
  for (int jt = 0; jt < JT; ++jt) {
    int col = jt * 16 + l15;
    #pragma unroll
    for (int r = 0; r < 4; ++r) {
      int orow = tile * 16 + l4 * 4 + r;
      if constexpr (DUAL) {
        float v1 = acc1[jt][r];
        float v2 = acc2[jt][r] + bv[jt];
        if constexpr (POUT) {
          float p1 = __shfl_xor(v1, 1);
          float p2 = __shfl_xor(v2, 1);
          if (((lane & 1) == 0) && col < F_OUT) {
            ((uint32_t*)C1v)[(size_t)orow * (F_OUT / 2) + (col >> 1)] = pack2(v1, p1);
            ((uint32_t*)C2v)[(size_t)orow * (F_OUT / 2) + (col >> 1)] = pack2(v2, p2);
          }
        } else {
          if (col < F_OUT) {
            ((float*)C1v)[(size_t)orow * F_OUT + col] = v1;
            ((float*)C2v)[(size_t)orow * F_OUT + col] = v2;
          }
        }
      } else {
        float v = acc1[jt][r] + bv[jt];
        if constexpr (RELU) v = fmaxf(v, 0.f);
        if constexpr (POUT) {
          float pv = __shfl_xor(v, 1);
          if (((lane & 1) == 0) && col < F_OUT)
            ((uint32_t*)C1v)[(size_t)orow * (F_OUT / 2) + (col >> 1)] = pack2(v, pv);
        } else {
          if (col < F_OUT)
            ((float*)C1v)[(size_t)orow * F_OUT + col] = v;
        }
      }
    }
  }
}

extern "C" void kernel_launch(void* const* d_in, const int* in_sizes, int n_in,
                              void* d_out, int out_size, void* d_ws, size_t ws_size,
                              hipStream_t stream) {
  const uint32_t* xw = (const uint32_t*)d_in[0];
  const uint32_t* ei = (const uint32_t*)d_in[1];

  char* ws = (char*)d_ws;
  size_t off = 0;
  auto carve = [&](size_t bytes) -> char* {
    char* p = ws + off;
    off = (off + bytes + 255) & ~(size_t)255;
    return p;
  };
  int* flags     = (int*)carve(8);
  int* deg       = (int*)carve((size_t)NNODES * 4);
  int* offs      = (int*)carve((size_t)(NNODES + 1) * 4);
  int* cursor    = (int*)carve((size_t)NNODES * 4);
  float* invd    = (float*)carve((size_t)NNODES * 4);
  int* bsum      = (int*)carve((size_t)NB * 4);
  int* csr       = (int*)carve((size_t)NEDGES * 4);
  float* wf      = (float*)carve((size_t)32768 * 4);
  uint32_t* xp   = (uint32_t*)carve((size_t)NNODES * 20 * 4);
  uint32_t* mp   = (uint32_t*)carve((size_t)NNODES * 20 * 4);
  uint32_t* b0p  = (uint32_t*)carve((size_t)NNODES * 32 * 4);
  uint32_t* b1p  = (uint32_t*)carve((size_t)NNODES * 32 * 4);
  uint32_t* b2p  = (uint32_t*)carve((size_t)NNODES * 32 * 4);
  uint32_t* y40p = (uint32_t*)carve((size_t)NNODES * 20 * 4);
  uint32_t* u40p = (uint32_t*)carve((size_t)NNODES * 20 * 4);
  uint32_t* xrp  = (uint32_t*)carve((size_t)NNODES * 20 * 4);
  float* y3f     = (float*)carve((size_t)NNODES * 3 * 4);
  float* u3f     = (float*)carve((size_t)NNODES * 3 * 4);
  float* zf      = (float*)carve((size_t)NNODES * 3 * 4);
  float* m3f     = (float*)carve((size_t)NNODES * 3 * 4);

  static const int wsz[18] = {2560, 2560, 64, 4096, 4096, 64, 192, 192, 3,
                              192, 192, 64, 4096, 4096, 64, 2560, 2560, 40};
  WPtrs wp;
  int woff = 0;
  for (int i = 0; i < 18; ++i) {
    wp.p[i] = d_in[2 + i];
    wp.sz[i] = wsz[i];
    wp.off[i] = woff;
    woff += wsz[i];
  }
  const float* W[18];
  for (int i = 0; i < 18; ++i) W[i] = wf + wp.off[i];

  // ---- detect + CSR build ----
  detect_k<<<1, 64, 0, stream>>>(xw, ei, flags);
  zero_i32<<<(NNODES + 255) / 256, 256, 0, stream>>>(deg, NNODES);
  hist_k<<<(NEDGES + 255) / 256, 256, 0, stream>>>(ei, deg, flags);
  scan1_k<<<NB, 1024, 0, stream>>>(deg, bsum);
  scan2_k<<<1, 64, 0, stream>>>(bsum, offs);
  scan3_k<<<NB, 1024, 0, stream>>>(deg, bsum, offs, cursor, invd);
  // 4-pass windowed scatter: each pass's csr window ~1.6MB stays L2-resident
  const int EB = (NEDGES + 255) / 256;
  scatter4_k<<<EB, 256, 0, stream>>>(ei, cursor, csr, flags, 0, 25000);
  scatter4_k<<<EB, 256, 0, stream>>>(ei, cursor, csr, flags, 25000, 50000);
  scatter4_k<<<EB, 256, 0, stream>>>(ei, cursor, csr, flags, 50000, 75000);
  scatter4_k<<<EB, 256, 0, stream>>>(ei, cursor, csr, flags, 75000, 100000);

  // ---- convert x (packed) + weights (f32 arena), flag-gated ----
  const int NXP = NNODES * 20;
  cvt_packx_k<false><<<(NXP + 255) / 256, 256, 0, stream>>>(d_in[0], xp, NXP, flags);
  cvt_packx_k<true ><<<(NXP + 255) / 256, 256, 0, stream>>>(d_in[0], xp, NXP, flags);
  cvt_w_k<false><<<18, 256, 0, stream>>>(wp, wf, flags);
  cvt_w_k<true ><<<18, 256, 0, stream>>>(wp, wf, flags);

  const int AGGW_BLOCKS = (NNODES * 64 + 255) / 256;   // 1 node per wave
  const int AGG3_BLOCKS = (NNODES + 255) / 256;        // 1 node per lane
  const int MG = (NNODES / 16 + 3) / 4;

  // enc1 (40 -> 64)
  aggp2_k<20, false><<<AGGW_BLOCKS, 256, 0, stream>>>(xp, csr, offs, invd, nullptr, mp);
  mgemm_k<40, 64, false, true, true, true><<<MG, 256, 0, stream>>>(mp, xp, W[0], W[1], W[2], b1p, nullptr);
  // enc2 (64 -> 64)
  aggp2_k<32, false><<<AGGW_BLOCKS, 256, 0, stream>>>(b1p, csr, offs, invd, nullptr, b0p);
  mgemm_k<64, 64, false, true, true, true><<<MG, 256, 0, stream>>>(b0p, b1p, W[3], W[4], W[5], b2p, nullptr);
  // enc3 (64 -> 3): transform-first; z path f32
  mgemm_k<64, 3, true, false, true, false><<<MG, 256, 0, stream>>>(b2p, nullptr, W[6], W[7], W[8], y3f, u3f);
  agg3_k<true><<<AGG3_BLOCKS, 256, 0, stream>>>(y3f, csr, offs, invd, u3f, zf);
  // dec1 (3 -> 64)
  agg3_k<false><<<AGG3_BLOCKS, 256, 0, stream>>>(zf, csr, offs, invd, nullptr, m3f);
  mgemm_k<3, 64, false, true, false, true><<<MG, 256, 0, stream>>>(m3f, zf, W[9], W[10], W[11], b1p, nullptr);
  // dec2 (64 -> 64)
  aggp2_k<32, false><<<AGGW_BLOCKS, 256, 0, stream>>>(b1p, csr, offs, invd, nullptr, b0p);
  mgemm_k<64, 64, false, true, true, true><<<MG, 256, 0, stream>>>(b0p, b1p, W[12], W[13], W[14], b2p, nullptr);
  // dec3 (64 -> 40): transform-first
  mgemm_k<64, 40, true, false, true, true><<<MG, 256, 0, stream>>>(b2p, nullptr, W[15], W[16], W[17], y40p, u40p);
  aggp2_k<20, true><<<AGGW_BLOCKS, 256, 0, stream>>>(y40p, csr, offs, invd, u40p, xrp);

  // ---- outputs ----
  const int NX = NNODES * 40;
  const int NZ = NNODES * 3;
  cvt_outp_k<false><<<(NXP + 255) / 256, 256, 0, stream>>>(xrp, d_out, NXP, flags);
  cvt_outp_k<true ><<<(NXP + 255) / 256, 256, 0, stream>>>(xrp, d_out, NXP, flags);
  cvt_out_k<false><<<(NZ + 255) / 256, 256, 0, stream>>>(zf, (float*)d_out + NX, NZ, flags);
  cvt_out_k<true ><<<(NZ + 255) / 256, 256, 0, stream>>>(zf, (ushort_t*)d_out + NX, NZ, flags);
  (void)in_sizes; (void)n_in; (void)out_size; (void)ws_size;
}